// Round 4
// baseline (283.325 us; speedup 1.0000x reference)
//
#include <hip/hip_runtime.h>
#include <math.h>

#define NH 8
#define HD 64
#define NSEQ 1024
#define DMODEL 512
#define F3 1536
#define NTOK 16384
#define BH 128    // (B*T)*NH = 16*8
#define KVP 72    // attn epilogue LDS pitch (bf16)
#define TP 136    // qkv epilogue transpose pitch (bf16)
#define QSCALE 0.1803368867f  // 0.125 * log2(e), folded into q; p = exp2(s')

typedef __attribute__((ext_vector_type(8))) short bf16x8;
typedef __attribute__((ext_vector_type(4))) float f32x4;
typedef __attribute__((ext_vector_type(16))) float f32x16;
typedef __attribute__((ext_vector_type(4))) unsigned int u32x4;
#define MFMA16(a, b, c) __builtin_amdgcn_mfma_f32_16x16x32_bf16(a, b, c, 0, 0, 0)
#define MFMA32(a, b, c) __builtin_amdgcn_mfma_f32_32x32x16_bf16(a, b, c, 0, 0, 0)

__device__ __forceinline__ float freq_of(int j) {
    return 3.14159265358979323846f * (1.0f + (float)j * (127.0f / 15.0f));
}
__device__ __forceinline__ unsigned short bf16_hi(float x) {
    unsigned u = __builtin_bit_cast(unsigned, x);
    return (unsigned short)(u >> 16);   // truncation split; residual goes to lo
}
__device__ __forceinline__ unsigned short bf16_rtn(float x) {
    unsigned u = __builtin_bit_cast(unsigned, x);
    return (unsigned short)((u + 0x7FFF + ((u >> 16) & 1)) >> 16);  // round-nearest-even
}
__device__ __forceinline__ float bf16_tofloat(unsigned short h) {
    unsigned u = ((unsigned)h) << 16;
    return __builtin_bit_cast(float, u);
}
// 2-bit LDS swizzle key for row r (permutes 16-B col-groups within a 64-B row)
__device__ __forceinline__ int swz(int r) { return (r & 3) ^ ((r >> 2) & 3); }

// ---------------- Kernel 0a: split fp32 -> bf16 hi/lo (trunc) ----------------
__global__ __launch_bounds__(256) void split_kernel(
        const float* __restrict__ src, unsigned short* __restrict__ hi,
        unsigned short* __restrict__ lo) {
    const int i = blockIdx.x * 256 + threadIdx.x;
    const float4 v = ((const float4*)src)[i];
    ushort4 h, l;
    h.x = bf16_hi(v.x); l.x = bf16_hi(v.x - bf16_tofloat(h.x));
    h.y = bf16_hi(v.y); l.y = bf16_hi(v.y - bf16_tofloat(h.y));
    h.z = bf16_hi(v.z); l.z = bf16_hi(v.z - bf16_tofloat(h.z));
    h.w = bf16_hi(v.w); l.w = bf16_hi(v.w - bf16_tofloat(h.w));
    ((ushort4*)hi)[i] = h;
    ((ushort4*)lo)[i] = l;
}
// ---------------- Kernel 0b: fp32 -> bf16 RTN single plane ----------------
__global__ __launch_bounds__(256) void cvt_kernel(
        const float* __restrict__ src, unsigned short* __restrict__ dst) {
    const int i = blockIdx.x * 256 + threadIdx.x;
    const float4 v = ((const float4*)src)[i];
    ((ushort4*)dst)[i] = make_ushort4(bf16_rtn(v.x), bf16_rtn(v.y),
                                      bf16_rtn(v.z), bf16_rtn(v.w));
}

// ---- register-staged pipelined GEMM core: 128x(128*NREP) tile, BK=32, 4 waves ----
// A planes = PLANES-1 ({A_hi,A_lo} or {A}); B planes = NREP (f0, f0+128, ...).
// Global->VGPR loads for kt+1 issued BEFORE compute(kt); ds_write after; one
// barrier/iter.
template<int PLANES, int NREP>
__device__ __forceinline__ void gemm_reg_pipe(
        const unsigned short* __restrict__ a_hi, const unsigned short* __restrict__ a_lo,
        const unsigned short* __restrict__ b_bf,
        char* lds, int m0, int f0, int t, f32x4 (&acc)[NREP][4][4]) {
    const int w = t >> 6, lane = t & 63, l15 = lane & 15, quad = lane >> 4;
    const int mw = (w & 1) * 64, nw = (w >> 1) * 64;
    const int APL = PLANES - 1;           // A planes
    const int NPL = APL + NREP;           // total planes
    const int STAGE = NPL * 4096;         // elements per stage
    const int r = t >> 1;                 // 0..127: row this thread stages
    const int g0 = (t & 1) * 2;           // first of two 16-B col-groups

    uint4 regs[NPL][2];
    auto load_regs = [&](int kt) {
        const int k0 = kt * 32;
        #pragma unroll
        for (int p = 0; p < NPL; p++) {
            const unsigned short* src = (p < APL) ? (p == 0 ? a_hi : a_lo) : b_bf;
            const int row0 = (p < APL) ? m0 : (f0 + (p - APL) * 128);
            const unsigned short* g = src + (size_t)(row0 + r) * DMODEL + k0 + g0 * 8;
            regs[p][0] = *(const uint4*)g;
            regs[p][1] = *(const uint4*)(g + 8);
        }
    };
    auto store_lds = [&](int stage) {
        unsigned short* S = (unsigned short*)lds + stage * STAGE;
        const int s0 = ((g0 ^ swz(r))) * 8;
        const int s1 = (((g0 + 1) ^ swz(r))) * 8;
        #pragma unroll
        for (int p = 0; p < NPL; p++) {
            unsigned short* Sp = S + p * 4096 + r * 32;
            *(uint4*)&Sp[s0] = regs[p][0];
            *(uint4*)&Sp[s1] = regs[p][1];
        }
    };

    load_regs(0);
    store_lds(0);
    for (int kt = 0; kt < 16; kt++) {
        __syncthreads();                  // stage (kt&1) visible to all waves
        if (kt < 15) load_regs(kt + 1);   // issue next tile's global loads NOW
        const unsigned short* S = (const unsigned short*)lds + (kt & 1) * STAGE;
        bf16x8 ah[4], al[4];
        #pragma unroll
        for (int mt = 0; mt < 4; mt++) {
            const int rr = mw + mt * 16 + l15;
            const int off = rr * 32 + (quad ^ swz(rr)) * 8;
            ah[mt] = *(const bf16x8*)&S[off];
            if (APL == 2) al[mt] = *(const bf16x8*)&S[4096 + off];
        }
        #pragma unroll
        for (int nr = 0; nr < NREP; nr++) {
            bf16x8 bb[4];
            #pragma unroll
            for (int nt = 0; nt < 4; nt++) {
                const int rr = nw + nt * 16 + l15;
                bb[nt] = *(const bf16x8*)&S[(APL + nr) * 4096 + rr * 32
                                            + (quad ^ swz(rr)) * 8];
            }
            #pragma unroll
            for (int mt = 0; mt < 4; mt++)
                #pragma unroll
                for (int nt = 0; nt < 4; nt++) {
                    acc[nr][mt][nt] = MFMA16(ah[mt], bb[nt], acc[nr][mt][nt]);
                    if (APL == 2) acc[nr][mt][nt] = MFMA16(al[mt], bb[nt], acc[nr][mt][nt]);
                }
        }
        if (kt < 15) store_lds((kt + 1) & 1);  // vmcnt wait lands here, post-MFMA
    }
    __syncthreads();                      // LDS free for epilogue reuse
}

// ---------------- Kernel 1: QKV GEMM + RoPE (128x256 tile, NREP=2) ----------------
// Outputs: q_bf (RTN, QSCALE folded), k_bf (RTN), v_th (RTN, transposed).
__global__ __launch_bounds__(256, 2) void qkv_mfma_kernel(
        const unsigned short* __restrict__ x_hi, const unsigned short* __restrict__ x_lo,
        const unsigned short* __restrict__ wq_bf,
        unsigned short* __restrict__ q_bf, unsigned short* __restrict__ k_bf,
        unsigned short* __restrict__ v_th) {
    __shared__ __align__(16) char lds[65536 + 4608];   // 2x32KB stages (+T alias) + tables
    unsigned short* T = (unsigned short*)lds;          // 128 x TP transpose buffer
    float* t_cy = (float*)(lds + 65536);               // [4][16]
    float* t_sy = t_cy + 64;
    float* t_cx = t_sy + 64;                           // [32][16]
    float* t_sx = t_cx + 512;

    const int m0 = blockIdx.x * 128;
    const int f0 = blockIdx.y * 256;
    const int t = threadIdx.x;
    const int w = t >> 6, lane = t & 63, l15 = lane & 15, quad = lane >> 4;
    const int mw = (w & 1) * 64, nw = (w >> 1) * 64;
    const int sel = f0 >> 9;                // 0=q,1=k,2=v (same for both subtiles)
    const int bt = m0 >> 10;
    const int n0 = m0 & 1023;

    if (sel != 2) {
        for (int idx = t; idx < 576; idx += 256) {
            if (idx < 64) {
                const int yi = idx >> 4, j = idx & 15;
                const float pos = -1.0f + (float)((n0 >> 5) + yi) * (2.0f / 31.0f);
                float sv, cv; sincosf(pos * freq_of(j), &sv, &cv);
                t_sy[idx] = sv; t_cy[idx] = cv;
            } else {
                const int k2 = idx - 64, xi = k2 >> 4, j = k2 & 15;
                const float pos = -1.0f + (float)xi * (2.0f / 31.0f);
                float sv, cv; sincosf(pos * freq_of(j), &sv, &cv);
                t_sx[k2] = sv; t_cx[k2] = cv;
            }
        }
    }
    __syncthreads();

    f32x4 acc[2][4][4];
    #pragma unroll
    for (int nr = 0; nr < 2; nr++)
        #pragma unroll
        for (int mt = 0; mt < 4; mt++)
            #pragma unroll
            for (int nt = 0; nt < 4; nt++) acc[nr][mt][nt] = (f32x4){0.f, 0.f, 0.f, 0.f};

    gemm_reg_pipe<3, 2>(x_hi, x_lo, wq_bf, lds, m0, f0, t, acc);

    #pragma unroll
    for (int nr = 0; nr < 2; nr++) {
        const int fs = f0 + nr * 128;
        // rope in place (q,k); q additionally scaled by QSCALE so attn uses exp2
        if (sel != 2) {
            const float post = (sel == 0) ? QSCALE : 1.0f;
            #pragma unroll
            for (int mt = 0; mt < 4; mt++)
                #pragma unroll
                for (int nt = 0; nt < 4; nt++)
                    #pragma unroll
                    for (int rr = 0; rr < 4; rr++) {
                        const int ml = mw + mt * 16 + quad * 4 + rr;
                        const int dd = (nw + nt * 16 + l15) & 63;
                        const int j0 = (dd & 31) >> 1;
                        float c, s;
                        if (dd < 32) { c = t_cy[(ml >> 5) * 16 + j0]; s = t_sy[(ml >> 5) * 16 + j0]; }
                        else         { c = t_cx[(ml & 31) * 16 + j0]; s = t_sx[(ml & 31) * 16 + j0]; }
                        const float v = acc[nr][mt][nt][rr];
                        const float pv = __shfl_xor(v, 1);
                        acc[nr][mt][nt][rr] =
                            ((l15 & 1) ? (v * c + pv * s) : (v * c - pv * s)) * post;
                    }
        }

        // single RTN pass through T; v transposed, q/k row-major
        if (sel == 2) {
            #pragma unroll
            for (int mt = 0; mt < 4; mt++)
                #pragma unroll
                for (int nt = 0; nt < 4; nt++) {
                    const int fl = nw + nt * 16 + l15;
                    const int mlb = mw + mt * 16 + quad * 4;
                    ushort4 pk = make_ushort4(
                        bf16_rtn(acc[nr][mt][nt][0]), bf16_rtn(acc[nr][mt][nt][1]),
                        bf16_rtn(acc[nr][mt][nt][2]), bf16_rtn(acc[nr][mt][nt][3]));
                    *(ushort4*)&T[fl * TP + mlb] = pk;
                }
        } else {
            #pragma unroll
            for (int mt = 0; mt < 4; mt++)
                #pragma unroll
                for (int nt = 0; nt < 4; nt++)
                    #pragma unroll
                    for (int rr = 0; rr < 4; rr++) {
                        const int ml = mw + mt * 16 + quad * 4 + rr;
                        const int fl = nw + nt * 16 + l15;
                        T[ml * TP + fl] = bf16_rtn(acc[nr][mt][nt][rr]);
                    }
        }
        __syncthreads();
        if (sel == 2) {
            #pragma unroll
            for (int p = 0; p < 8; p++) {
                const int idx = p * 256 + t;
                const int fl = idx >> 4, g8 = (idx & 15) * 8;
                const int head = ((fs + fl) >> 6) & 7;
                *(uint4*)(v_th + ((size_t)(bt * NH + head) * HD + ((fs + fl) & 63)) * NSEQ
                          + n0 + g8) = *(const uint4*)&T[fl * TP + g8];
            }
        } else {
            unsigned short* dst = (sel == 0) ? q_bf : k_bf;
            #pragma unroll
            for (int p = 0; p < 8; p++) {
                const int idx = p * 256 + t;
                const int ml = idx >> 4, g8 = (idx & 15) * 8;
                const int head = ((fs + g8) >> 6) & 7;
                *(uint4*)(dst + ((size_t)(bt * NH + head) * NSEQ + n0 + ml) * HD
                          + ((fs + g8) & 63)) = *(const uint4*)&T[ml * TP + g8];
            }
        }
        __syncthreads();
    }
}

// ---------------- Kernel 2: flash attention, direct-from-L2 K/V, no barriers ----
// Per bh, K+V = 256 KB and the (bh, qt) grid pins all 8 sharing blocks to one
// XCD -> K/V is L2-resident; LDS staging + per-tile barriers were pure overhead
// (2-phase lockstep stall). K and V fragments are read straight from global
// (L1/L2 hit); waves free-run; the only barrier is the epilogue Osh bounce.
// S^T = mfma32(K, Q): lane owns one q-row; softmax fully in-register via
// cvt_pk_bf16 + permlane32_swap; row-sum l via ones-B MFMA.
__global__ __launch_bounds__(256, 4) void attn_kernel(
        const unsigned short* __restrict__ q_bf, const unsigned short* __restrict__ k_bf,
        const unsigned short* __restrict__ v_th,
        unsigned short* __restrict__ o_bf) {
    __shared__ unsigned short Osh[128 * KVP];   // epilogue bounce only (18.4 KB)

    const int bh = blockIdx.x;     // fastest dim -> XCD = bh & 7 for all 8 qt blocks
    const int qt = blockIdx.y;     // 0..7
    const int t = threadIdx.x;
    const int w = t >> 6;
    const int lane = t & 63;
    const int l31 = lane & 31;
    const int hi = lane >> 5;

    const size_t bh_nd = (size_t)bh * NSEQ * HD;
    const size_t bh_dn = (size_t)bh * HD * NSEQ;

    // Q as B-fragments of mfma32 (B[k=d][col=qrow]): lane reads
    // Q[qrow = w*32 + l31][d = ds*16 + hi*8 + 0..7]; loaded once per block.
    bf16x8 qfB[4];
    {
        const size_t rbase = bh_nd + (size_t)(qt * 128 + w * 32 + l31) * HD + hi * 8;
        #pragma unroll
        for (int ds = 0; ds < 4; ds++)
            qfB[ds] = *(const bf16x8*)(q_bf + rbase + ds * 16);
    }

    // per-lane loop-invariant bases
    const unsigned short* Kl = k_bf + bh_nd + (size_t)l31 * HD + hi * 8;       // + n*HD
    const unsigned short* Vl = v_th + bh_dn + (size_t)l31 * NSEQ + hi * 8;     // + d*NSEQ + n

    const bf16x8 ones = {(short)0x3F80, (short)0x3F80, (short)0x3F80, (short)0x3F80,
                         (short)0x3F80, (short)0x3F80, (short)0x3F80, (short)0x3F80};

    f32x16 o_acc[2], l_acc;
    #pragma unroll
    for (int i = 0; i < 16; i++) {
        o_acc[0][i] = 0.f; o_acc[1][i] = 0.f; l_acc[i] = 0.f;
    }

    #pragma unroll 2
    for (int kt = 0; kt < 16; kt++) {
        const int n0k = kt * 64;
        #pragma unroll
        for (int nt2 = 0; nt2 < 2; nt2++) {
            // ---- K fragments for this 32-row strip (L1/L2 hit) ----
            bf16x8 kb[4];
            #pragma unroll
            for (int ds = 0; ds < 4; ds++)
                kb[ds] = *(const bf16x8*)(Kl + (size_t)(n0k + nt2 * 32) * HD + ds * 16);

            // ---- S^T = K · Q^T over d=64 (4 chained K=16 MFMAs) ----
            __builtin_amdgcn_s_setprio(1);
            f32x16 s;
            #pragma unroll
            for (int i = 0; i < 16; i++) s[i] = 0.f;
            #pragma unroll
            for (int ds = 0; ds < 4; ds++) s = MFMA32(kb[ds], qfB[ds], s);
            __builtin_amdgcn_s_setprio(0);

            // ---- V fragments for this strip's two ksteps: issue under softmax ----
            bf16x8 vb[2][2];
            #pragma unroll
            for (int k2 = 0; k2 < 2; k2++)
                #pragma unroll
                for (int dt = 0; dt < 2; dt++)
                    vb[k2][dt] = *(const bf16x8*)(Vl + (size_t)(dt * 32) * NSEQ
                                  + n0k + (nt2 * 2 + k2) * 16);

            // ---- p = exp2(s); pack pairs to bf16 words ----
            // lane holds P[qrow=l31][kcol = crow(r,hi)], crow = (r&3)+8*(r>>2)+4*hi
            unsigned wv[8];
            #pragma unroll
            for (int i = 0; i < 8; i++) {
                const float p0 = exp2f(s[2 * i]);
                const float p1 = exp2f(s[2 * i + 1]);
                asm("v_cvt_pk_bf16_f32 %0, %1, %2" : "=v"(wv[i]) : "v"(p0), "v"(p1));
            }
            // ---- exchange halves: vdst.hi <-> vsrc.lo (first operand = lower-k word)
            asm volatile("v_permlane32_swap_b32 %0, %1" : "+v"(wv[0]), "+v"(wv[2]));
            asm volatile("v_permlane32_swap_b32 %0, %1" : "+v"(wv[1]), "+v"(wv[3]));
            asm volatile("v_permlane32_swap_b32 %0, %1" : "+v"(wv[4]), "+v"(wv[6]));
            asm volatile("v_permlane32_swap_b32 %0, %1" : "+v"(wv[5]), "+v"(wv[7]));

            // ---- O += P·V, l += P·1 (P entirely in registers) ----
            __builtin_amdgcn_s_setprio(1);
            #pragma unroll
            for (int k2 = 0; k2 < 2; k2++) {
                const u32x4 paw = {wv[k2 * 4 + 0], wv[k2 * 4 + 1],
                                   wv[k2 * 4 + 2], wv[k2 * 4 + 3]};
                const bf16x8 pa = __builtin_bit_cast(bf16x8, paw);
                l_acc = MFMA32(pa, ones, l_acc);
                #pragma unroll
                for (int dt = 0; dt < 2; dt++)
                    o_acc[dt] = MFMA32(pa, vb[k2][dt], o_acc[dt]);
            }
            __builtin_amdgcn_s_setprio(0);
        }
    }

    // ---- epilogue: normalize by l; LDS bounce -> full-128B-line uint4 stores ----
    #pragma unroll
    for (int r = 0; r < 16; r++) {
        const float inv = 1.0f / l_acc[r];
        const int row = w * 32 + (r & 3) + 8 * (r >> 2) + 4 * hi;
        #pragma unroll
        for (int dt = 0; dt < 2; dt++)
            Osh[row * KVP + dt * 32 + l31] = bf16_rtn(o_acc[dt][r] * inv);
    }
    __syncthreads();
    const int btq = bh >> 3, head = bh & 7;
    #pragma unroll
    for (int p = 0; p < 4; p++) {
        const int idx = p * 256 + t;
        const int row = idx >> 3, g8 = (idx & 7) * 8;
        *(uint4*)(o_bf + ((size_t)(btq * NSEQ + qt * 128 + row)) * DMODEL
                  + head * HD + g8) = *(const uint4*)&Osh[row * KVP + g8];
    }
}

// ---------------- Kernel 3: output projection (2-plane, pipelined) ----------------
__global__ __launch_bounds__(256, 3) void proj_mfma_kernel(
        const unsigned short* __restrict__ o_bf,
        const unsigned short* __restrict__ wo_bf,
        const float* __restrict__ b_out, float* __restrict__ out) {
    __shared__ __align__(16) char lds[32768];   // 2 x 16KB stages

    const int m0 = blockIdx.x * 128;
    const int f0 = blockIdx.y * 128;
    const int t = threadIdx.x;
    const int w = t >> 6, lane = t & 63, l15 = lane & 15, quad = lane >> 4;
    const int mw = (w & 1) * 64, nw = (w >> 1) * 64;

    f32x4 acc[1][4][4];
    #pragma unroll
    for (int mt = 0; mt < 4; mt++)
        #pragma unroll
        for (int nt = 0; nt < 4; nt++) acc[0][mt][nt] = (f32x4){0.f, 0.f, 0.f, 0.f};

    gemm_reg_pipe<2, 1>(o_bf, o_bf, wo_bf, lds, m0, f0, t, acc);

    float bias_v[4];
    #pragma unroll
    for (int nt = 0; nt < 4; nt++) bias_v[nt] = b_out[f0 + nw + nt * 16 + l15];
    #pragma unroll
    for (int mt = 0; mt < 4; mt++)
        #pragma unroll
        for (int nt = 0; nt < 4; nt++)
            #pragma unroll
            for (int rr = 0; rr < 4; rr++) {
                const int m = m0 + mw + mt * 16 + quad * 4 + rr;
                out[(size_t)m * DMODEL + f0 + nw + nt * 16 + l15] =
                    acc[0][mt][nt][rr] + bias_v[nt];
            }
}

extern "C" void kernel_launch(void* const* d_in, const int* in_sizes, int n_in,
                              void* d_out, int out_size, void* d_ws, size_t ws_size,
                              hipStream_t stream) {
    const float* x  = (const float*)d_in[0];
    const float* wq = (const float*)d_in[1];
    const float* wo = (const float*)d_in[2];
    const float* bo = (const float*)d_in[3];
    float* out = (float*)d_out;

    const size_t per = (size_t)BH * NSEQ * HD;   // 8,388,608 elements
    unsigned short* x_hi = (unsigned short*)d_ws;   // reused as o_bf after qkv
    unsigned short* x_lo = x_hi + per;
    unsigned short* q_bf = x_lo + per;
    unsigned short* k_bf = q_bf + per;
    unsigned short* v_th = k_bf + per;
    unsigned short* wq_bf = v_th + per;                   // 786,432 els
    unsigned short* wo_bf = wq_bf + (size_t)F3 * DMODEL;  // 262,144 els (~82 MiB total)
    unsigned short* o_bf = x_hi;   // x dead after qkv

    split_kernel<<<dim3((int)(per / 1024)), 256, 0, stream>>>(x, x_hi, x_lo);
    cvt_kernel<<<dim3(F3 * DMODEL / 1024), 256, 0, stream>>>(wq, wq_bf);
    cvt_kernel<<<dim3(DMODEL * DMODEL / 1024), 256, 0, stream>>>(wo, wo_bf);
    qkv_mfma_kernel<<<dim3(NTOK / 128, F3 / 256), 256, 0, stream>>>(
        x_hi, x_lo, wq_bf, q_bf, k_bf, v_th);
    attn_kernel<<<dim3(BH, 8), 256, 0, stream>>>(
        q_bf, k_bf, v_th, o_bf);
    proj_mfma_kernel<<<dim3(NTOK / 128, DMODEL / 128), 256, 0, stream>>>(
        o_bf, wo_bf, bo, out);
}

// Round 5
// 273.537 us; speedup vs baseline: 1.0358x; 1.0358x over previous
//
#include <hip/hip_runtime.h>
#include <math.h>

#define NH 8
#define HD 64
#define NSEQ 1024
#define DMODEL 512
#define F3 1536
#define NTOK 16384
#define BH 128    // (B*T)*NH = 16*8
#define KVP 72    // attn K/V LDS pitch (bf16)
#define TP 136    // qkv epilogue transpose pitch (bf16)
#define QSCALE 0.1803368867f  // 0.125 * log2(e), folded into q; p = exp2(s')

typedef __attribute__((ext_vector_type(8))) short bf16x8;
typedef __attribute__((ext_vector_type(4))) float f32x4;
typedef __attribute__((ext_vector_type(16))) float f32x16;
typedef __attribute__((ext_vector_type(4))) unsigned int u32x4;
#define MFMA16(a, b, c) __builtin_amdgcn_mfma_f32_16x16x32_bf16(a, b, c, 0, 0, 0)
#define MFMA32(a, b, c) __builtin_amdgcn_mfma_f32_32x32x16_bf16(a, b, c, 0, 0, 0)

__device__ __forceinline__ float freq_of(int j) {
    return 3.14159265358979323846f * (1.0f + (float)j * (127.0f / 15.0f));
}
__device__ __forceinline__ unsigned short bf16_hi(float x) {
    unsigned u = __builtin_bit_cast(unsigned, x);
    return (unsigned short)(u >> 16);   // truncation split; residual goes to lo
}
__device__ __forceinline__ unsigned short bf16_rtn(float x) {
    unsigned u = __builtin_bit_cast(unsigned, x);
    return (unsigned short)((u + 0x7FFF + ((u >> 16) & 1)) >> 16);  // round-nearest-even
}
__device__ __forceinline__ float bf16_tofloat(unsigned short h) {
    unsigned u = ((unsigned)h) << 16;
    return __builtin_bit_cast(float, u);
}
// 2-bit LDS swizzle key for row r (permutes 16-B col-groups within a 64-B row)
__device__ __forceinline__ int swz(int r) { return (r & 3) ^ ((r >> 2) & 3); }

// ---------------- Kernel 0a: split fp32 -> bf16 hi/lo (trunc) ----------------
__global__ __launch_bounds__(256) void split_kernel(
        const float* __restrict__ src, unsigned short* __restrict__ hi,
        unsigned short* __restrict__ lo) {
    const int i = blockIdx.x * 256 + threadIdx.x;
    const float4 v = ((const float4*)src)[i];
    ushort4 h, l;
    h.x = bf16_hi(v.x); l.x = bf16_hi(v.x - bf16_tofloat(h.x));
    h.y = bf16_hi(v.y); l.y = bf16_hi(v.y - bf16_tofloat(h.y));
    h.z = bf16_hi(v.z); l.z = bf16_hi(v.z - bf16_tofloat(h.z));
    h.w = bf16_hi(v.w); l.w = bf16_hi(v.w - bf16_tofloat(h.w));
    ((ushort4*)hi)[i] = h;
    ((ushort4*)lo)[i] = l;
}
// ---------------- Kernel 0b: fp32 -> bf16 RTN single plane ----------------
__global__ __launch_bounds__(256) void cvt_kernel(
        const float* __restrict__ src, unsigned short* __restrict__ dst) {
    const int i = blockIdx.x * 256 + threadIdx.x;
    const float4 v = ((const float4*)src)[i];
    ((ushort4*)dst)[i] = make_ushort4(bf16_rtn(v.x), bf16_rtn(v.y),
                                      bf16_rtn(v.z), bf16_rtn(v.w));
}

// ---- register-staged pipelined GEMM core: 128x(128*NREP) tile, BK=32, 4 waves ----
// A planes = PLANES-1 ({A_hi,A_lo} or {A}); B planes = NREP (f0, f0+128, ...).
// Global->VGPR loads for kt+1 issued BEFORE compute(kt); ds_write after; one
// barrier/iter.
template<int PLANES, int NREP>
__device__ __forceinline__ void gemm_reg_pipe(
        const unsigned short* __restrict__ a_hi, const unsigned short* __restrict__ a_lo,
        const unsigned short* __restrict__ b_bf,
        char* lds, int m0, int f0, int t, f32x4 (&acc)[NREP][4][4]) {
    const int w = t >> 6, lane = t & 63, l15 = lane & 15, quad = lane >> 4;
    const int mw = (w & 1) * 64, nw = (w >> 1) * 64;
    const int APL = PLANES - 1;           // A planes
    const int NPL = APL + NREP;           // total planes
    const int STAGE = NPL * 4096;         // elements per stage
    const int r = t >> 1;                 // 0..127: row this thread stages
    const int g0 = (t & 1) * 2;           // first of two 16-B col-groups

    uint4 regs[NPL][2];
    auto load_regs = [&](int kt) {
        const int k0 = kt * 32;
        #pragma unroll
        for (int p = 0; p < NPL; p++) {
            const unsigned short* src = (p < APL) ? (p == 0 ? a_hi : a_lo) : b_bf;
            const int row0 = (p < APL) ? m0 : (f0 + (p - APL) * 128);
            const unsigned short* g = src + (size_t)(row0 + r) * DMODEL + k0 + g0 * 8;
            regs[p][0] = *(const uint4*)g;
            regs[p][1] = *(const uint4*)(g + 8);
        }
    };
    auto store_lds = [&](int stage) {
        unsigned short* S = (unsigned short*)lds + stage * STAGE;
        const int s0 = ((g0 ^ swz(r))) * 8;
        const int s1 = (((g0 + 1) ^ swz(r))) * 8;
        #pragma unroll
        for (int p = 0; p < NPL; p++) {
            unsigned short* Sp = S + p * 4096 + r * 32;
            *(uint4*)&Sp[s0] = regs[p][0];
            *(uint4*)&Sp[s1] = regs[p][1];
        }
    };

    load_regs(0);
    store_lds(0);
    for (int kt = 0; kt < 16; kt++) {
        __syncthreads();                  // stage (kt&1) visible to all waves
        if (kt < 15) load_regs(kt + 1);   // issue next tile's global loads NOW
        const unsigned short* S = (const unsigned short*)lds + (kt & 1) * STAGE;
        bf16x8 ah[4], al[4];
        #pragma unroll
        for (int mt = 0; mt < 4; mt++) {
            const int rr = mw + mt * 16 + l15;
            const int off = rr * 32 + (quad ^ swz(rr)) * 8;
            ah[mt] = *(const bf16x8*)&S[off];
            if (APL == 2) al[mt] = *(const bf16x8*)&S[4096 + off];
        }
        #pragma unroll
        for (int nr = 0; nr < NREP; nr++) {
            bf16x8 bb[4];
            #pragma unroll
            for (int nt = 0; nt < 4; nt++) {
                const int rr = nw + nt * 16 + l15;
                bb[nt] = *(const bf16x8*)&S[(APL + nr) * 4096 + rr * 32
                                            + (quad ^ swz(rr)) * 8];
            }
            #pragma unroll
            for (int mt = 0; mt < 4; mt++)
                #pragma unroll
                for (int nt = 0; nt < 4; nt++) {
                    acc[nr][mt][nt] = MFMA16(ah[mt], bb[nt], acc[nr][mt][nt]);
                    if (APL == 2) acc[nr][mt][nt] = MFMA16(al[mt], bb[nt], acc[nr][mt][nt]);
                }
        }
        if (kt < 15) store_lds((kt + 1) & 1);  // vmcnt wait lands here, post-MFMA
    }
    __syncthreads();                      // LDS free for epilogue reuse
}

// ---------------- Kernel 1: QKV GEMM + RoPE (128x256 tile, NREP=2) ----------------
// Outputs: q_bf (RTN, QSCALE folded), k_bf (RTN), v_th (RTN, transposed).
__global__ __launch_bounds__(256, 2) void qkv_mfma_kernel(
        const unsigned short* __restrict__ x_hi, const unsigned short* __restrict__ x_lo,
        const unsigned short* __restrict__ wq_bf,
        unsigned short* __restrict__ q_bf, unsigned short* __restrict__ k_bf,
        unsigned short* __restrict__ v_th) {
    __shared__ __align__(16) char lds[65536 + 4608];   // 2x32KB stages (+T alias) + tables
    unsigned short* T = (unsigned short*)lds;          // 128 x TP transpose buffer
    float* t_cy = (float*)(lds + 65536);               // [4][16]
    float* t_sy = t_cy + 64;
    float* t_cx = t_sy + 64;                           // [32][16]
    float* t_sx = t_cx + 512;

    const int m0 = blockIdx.x * 128;
    const int f0 = blockIdx.y * 256;
    const int t = threadIdx.x;
    const int w = t >> 6, lane = t & 63, l15 = lane & 15, quad = lane >> 4;
    const int mw = (w & 1) * 64, nw = (w >> 1) * 64;
    const int sel = f0 >> 9;                // 0=q,1=k,2=v (same for both subtiles)
    const int bt = m0 >> 10;
    const int n0 = m0 & 1023;

    if (sel != 2) {
        for (int idx = t; idx < 576; idx += 256) {
            if (idx < 64) {
                const int yi = idx >> 4, j = idx & 15;
                const float pos = -1.0f + (float)((n0 >> 5) + yi) * (2.0f / 31.0f);
                float sv, cv; sincosf(pos * freq_of(j), &sv, &cv);
                t_sy[idx] = sv; t_cy[idx] = cv;
            } else {
                const int k2 = idx - 64, xi = k2 >> 4, j = k2 & 15;
                const float pos = -1.0f + (float)xi * (2.0f / 31.0f);
                float sv, cv; sincosf(pos * freq_of(j), &sv, &cv);
                t_sx[k2] = sv; t_cx[k2] = cv;
            }
        }
    }
    __syncthreads();

    f32x4 acc[2][4][4];
    #pragma unroll
    for (int nr = 0; nr < 2; nr++)
        #pragma unroll
        for (int mt = 0; mt < 4; mt++)
            #pragma unroll
            for (int nt = 0; nt < 4; nt++) acc[nr][mt][nt] = (f32x4){0.f, 0.f, 0.f, 0.f};

    gemm_reg_pipe<3, 2>(x_hi, x_lo, wq_bf, lds, m0, f0, t, acc);

    #pragma unroll
    for (int nr = 0; nr < 2; nr++) {
        const int fs = f0 + nr * 128;
        // rope in place (q,k); q additionally scaled by QSCALE so attn uses exp2
        if (sel != 2) {
            const float post = (sel == 0) ? QSCALE : 1.0f;
            #pragma unroll
            for (int mt = 0; mt < 4; mt++)
                #pragma unroll
                for (int nt = 0; nt < 4; nt++)
                    #pragma unroll
                    for (int rr = 0; rr < 4; rr++) {
                        const int ml = mw + mt * 16 + quad * 4 + rr;
                        const int dd = (nw + nt * 16 + l15) & 63;
                        const int j0 = (dd & 31) >> 1;
                        float c, s;
                        if (dd < 32) { c = t_cy[(ml >> 5) * 16 + j0]; s = t_sy[(ml >> 5) * 16 + j0]; }
                        else         { c = t_cx[(ml & 31) * 16 + j0]; s = t_sx[(ml & 31) * 16 + j0]; }
                        const float v = acc[nr][mt][nt][rr];
                        const float pv = __shfl_xor(v, 1);
                        acc[nr][mt][nt][rr] =
                            ((l15 & 1) ? (v * c + pv * s) : (v * c - pv * s)) * post;
                    }
        }

        // single RTN pass through T; v transposed, q/k row-major
        if (sel == 2) {
            #pragma unroll
            for (int mt = 0; mt < 4; mt++)
                #pragma unroll
                for (int nt = 0; nt < 4; nt++) {
                    const int fl = nw + nt * 16 + l15;
                    const int mlb = mw + mt * 16 + quad * 4;
                    ushort4 pk = make_ushort4(
                        bf16_rtn(acc[nr][mt][nt][0]), bf16_rtn(acc[nr][mt][nt][1]),
                        bf16_rtn(acc[nr][mt][nt][2]), bf16_rtn(acc[nr][mt][nt][3]));
                    *(ushort4*)&T[fl * TP + mlb] = pk;
                }
        } else {
            #pragma unroll
            for (int mt = 0; mt < 4; mt++)
                #pragma unroll
                for (int nt = 0; nt < 4; nt++)
                    #pragma unroll
                    for (int rr = 0; rr < 4; rr++) {
                        const int ml = mw + mt * 16 + quad * 4 + rr;
                        const int fl = nw + nt * 16 + l15;
                        T[ml * TP + fl] = bf16_rtn(acc[nr][mt][nt][rr]);
                    }
        }
        __syncthreads();
        if (sel == 2) {
            #pragma unroll
            for (int p = 0; p < 8; p++) {
                const int idx = p * 256 + t;
                const int fl = idx >> 4, g8 = (idx & 15) * 8;
                const int head = ((fs + fl) >> 6) & 7;
                *(uint4*)(v_th + ((size_t)(bt * NH + head) * HD + ((fs + fl) & 63)) * NSEQ
                          + n0 + g8) = *(const uint4*)&T[fl * TP + g8];
            }
        } else {
            unsigned short* dst = (sel == 0) ? q_bf : k_bf;
            #pragma unroll
            for (int p = 0; p < 8; p++) {
                const int idx = p * 256 + t;
                const int ml = idx >> 4, g8 = (idx & 15) * 8;
                const int head = ((fs + g8) >> 6) & 7;
                *(uint4*)(dst + ((size_t)(bt * NH + head) * NSEQ + n0 + ml) * HD
                          + ((fs + g8) & 63)) = *(const uint4*)&T[ml * TP + g8];
            }
        }
        __syncthreads();
    }
}

// ---------------- Kernel 2: flash attention, swapped-QK^T 32x32, in-register P ----
// LDS-staged K/V (4-wave reuse; round-4 direct-L2 variant was 4x L2 traffic and
// latency-bound). 4 blocks/CU co-resident (grid = exactly 4x256) so barrier
// drains overlap across blocks. S seeded from persistent zero16 C-operand.
// V ds_reads hoisted above exp2 so lgkmcnt hides under softmax VALU.
__global__ __launch_bounds__(256, 4) void attn_kernel(
        const unsigned short* __restrict__ q_bf, const unsigned short* __restrict__ k_bf,
        const unsigned short* __restrict__ v_th,
        unsigned short* __restrict__ o_bf) {
    __shared__ unsigned short Ks[2][64 * KVP];  // K tile [n][d], double-buffered
    __shared__ unsigned short Vs[2][64 * KVP];  // V^T tile [d][n], double-buffered

    const int bh = blockIdx.x;     // fastest dim -> XCD = bh & 7 for all 8 qt blocks
    const int qt = blockIdx.y;     // 0..7
    const int t = threadIdx.x;
    const int w = t >> 6;
    const int lane = t & 63;
    const int l31 = lane & 31;
    const int hi = lane >> 5;

    const size_t bh_nd = (size_t)bh * NSEQ * HD;
    const size_t bh_dn = (size_t)bh * HD * NSEQ;

    // Q as B-fragments of mfma32 (B[k=d][col=qrow]): lane reads
    // Q[qrow = w*32 + l31][d = ds*16 + hi*8 + 0..7]; loaded once per block.
    bf16x8 qfB[4];
    {
        const size_t rbase = bh_nd + (size_t)(qt * 128 + w * 32 + l31) * HD + hi * 8;
        #pragma unroll
        for (int ds = 0; ds < 4; ds++)
            qfB[ds] = *(const bf16x8*)(q_bf + rbase + ds * 16);
    }

    uint4 kr[2], vr[2];
    auto load_kv = [&](int kt) {
        #pragma unroll
        for (int p = 0; p < 2; p++) {
            const int cc = t + p * 256;
            const int r = cc >> 3, off8 = (cc & 7) * 8;
            kr[p] = *(const uint4*)(k_bf + bh_nd + (size_t)(kt * 64 + r) * HD + off8);
            vr[p] = *(const uint4*)(v_th + bh_dn + (size_t)r * NSEQ + kt * 64 + off8);
        }
    };
    auto store_kv = [&](int st) {
        #pragma unroll
        for (int p = 0; p < 2; p++) {
            const int cc = t + p * 256;
            const int r = cc >> 3, off8 = (cc & 7) * 8;
            *(uint4*)&Ks[st][r * KVP + off8] = kr[p];
            *(uint4*)&Vs[st][r * KVP + off8] = vr[p];
        }
    };

    const bf16x8 ones = {(short)0x3F80, (short)0x3F80, (short)0x3F80, (short)0x3F80,
                         (short)0x3F80, (short)0x3F80, (short)0x3F80, (short)0x3F80};

    f32x16 o_acc[2], l_acc, zero16;
    #pragma unroll
    for (int i = 0; i < 16; i++) {
        o_acc[0][i] = 0.f; o_acc[1][i] = 0.f; l_acc[i] = 0.f; zero16[i] = 0.f;
    }

    load_kv(0);
    store_kv(0);
    for (int kt = 0; kt < 16; kt++) {
        __syncthreads();                  // stage (kt&1) visible
        if (kt < 15) load_kv(kt + 1);     // prefetch next tile into VGPRs
        const unsigned short* K = Ks[kt & 1];
        const unsigned short* V = Vs[kt & 1];

        #pragma unroll
        for (int nt2 = 0; nt2 < 2; nt2++) {
            // ---- K and V fragments from LDS (V early: lgkm hides under exp2) ----
            bf16x8 kb[4];
            #pragma unroll
            for (int ds = 0; ds < 4; ds++)
                kb[ds] = *(const bf16x8*)&K[(nt2 * 32 + l31) * KVP + ds * 16 + hi * 8];
            bf16x8 vbr[2][2];
            #pragma unroll
            for (int k2 = 0; k2 < 2; k2++)
                #pragma unroll
                for (int dt = 0; dt < 2; dt++)
                    vbr[k2][dt] = *(const bf16x8*)&V[(dt * 32 + l31) * KVP
                                      + (nt2 * 2 + k2) * 16 + hi * 8];

            // ---- S^T = K · Q^T over d=64 (zero16-seeded, no acc re-init) ----
            __builtin_amdgcn_s_setprio(1);
            f32x16 s = MFMA32(kb[0], qfB[0], zero16);
            #pragma unroll
            for (int ds = 1; ds < 4; ds++) s = MFMA32(kb[ds], qfB[ds], s);
            __builtin_amdgcn_s_setprio(0);

            // ---- p = exp2(s); pack pairs to bf16 words ----
            // lane holds P[qrow=l31][kcol = crow(r,hi)], crow = (r&3)+8*(r>>2)+4*hi
            unsigned wv[8];
            #pragma unroll
            for (int i = 0; i < 8; i++) {
                const float p0 = exp2f(s[2 * i]);
                const float p1 = exp2f(s[2 * i + 1]);
                asm("v_cvt_pk_bf16_f32 %0, %1, %2" : "=v"(wv[i]) : "v"(p0), "v"(p1));
            }
            // ---- exchange halves: vdst.hi <-> vsrc.lo (first operand = lower-k word)
            asm volatile("v_permlane32_swap_b32 %0, %1" : "+v"(wv[0]), "+v"(wv[2]));
            asm volatile("v_permlane32_swap_b32 %0, %1" : "+v"(wv[1]), "+v"(wv[3]));
            asm volatile("v_permlane32_swap_b32 %0, %1" : "+v"(wv[4]), "+v"(wv[6]));
            asm volatile("v_permlane32_swap_b32 %0, %1" : "+v"(wv[5]), "+v"(wv[7]));

            // ---- O += P·V, l += P·1 (P entirely in registers) ----
            __builtin_amdgcn_s_setprio(1);
            #pragma unroll
            for (int k2 = 0; k2 < 2; k2++) {
                const u32x4 paw = {wv[k2 * 4 + 0], wv[k2 * 4 + 1],
                                   wv[k2 * 4 + 2], wv[k2 * 4 + 3]};
                const bf16x8 pa = __builtin_bit_cast(bf16x8, paw);
                l_acc = MFMA32(pa, ones, l_acc);
                #pragma unroll
                for (int dt = 0; dt < 2; dt++)
                    o_acc[dt] = MFMA32(pa, vbr[k2][dt], o_acc[dt]);
            }
            __builtin_amdgcn_s_setprio(0);
        }
        if (kt < 15) store_kv((kt + 1) & 1);  // vmcnt wait lands post-MFMA
    }

    // ---- epilogue: normalize by l; LDS bounce -> full-128B-line uint4 stores ----
    __syncthreads();                       // all waves done reading Ks/Vs
    unsigned short* Osh = &Ks[0][0];       // 128 rows x KVP pitch = 9216 els, exact fit
    #pragma unroll
    for (int r = 0; r < 16; r++) {
        const float inv = 1.0f / l_acc[r];
        const int row = w * 32 + (r & 3) + 8 * (r >> 2) + 4 * hi;
        #pragma unroll
        for (int dt = 0; dt < 2; dt++)
            Osh[row * KVP + dt * 32 + l31] = bf16_rtn(o_acc[dt][r] * inv);
    }
    __syncthreads();
    const int btq = bh >> 3, head = bh & 7;
    #pragma unroll
    for (int p = 0; p < 4; p++) {
        const int idx = p * 256 + t;
        const int row = idx >> 3, g8 = (idx & 7) * 8;
        *(uint4*)(o_bf + ((size_t)(btq * NSEQ + qt * 128 + row)) * DMODEL
                  + head * HD + g8) = *(const uint4*)&Osh[row * KVP + g8];
    }
}

// ---------------- Kernel 3: output projection (2-plane, pipelined) ----------------
__global__ __launch_bounds__(256, 3) void proj_mfma_kernel(
        const unsigned short* __restrict__ o_bf,
        const unsigned short* __restrict__ wo_bf,
        const float* __restrict__ b_out, float* __restrict__ out) {
    __shared__ __align__(16) char lds[32768];   // 2 x 16KB stages

    const int m0 = blockIdx.x * 128;
    const int f0 = blockIdx.y * 128;
    const int t = threadIdx.x;
    const int w = t >> 6, lane = t & 63, l15 = lane & 15, quad = lane >> 4;
    const int mw = (w & 1) * 64, nw = (w >> 1) * 64;

    f32x4 acc[1][4][4];
    #pragma unroll
    for (int mt = 0; mt < 4; mt++)
        #pragma unroll
        for (int nt = 0; nt < 4; nt++) acc[0][mt][nt] = (f32x4){0.f, 0.f, 0.f, 0.f};

    gemm_reg_pipe<2, 1>(o_bf, o_bf, wo_bf, lds, m0, f0, t, acc);

    float bias_v[4];
    #pragma unroll
    for (int nt = 0; nt < 4; nt++) bias_v[nt] = b_out[f0 + nw + nt * 16 + l15];
    #pragma unroll
    for (int mt = 0; mt < 4; mt++)
        #pragma unroll
        for (int nt = 0; nt < 4; nt++)
            #pragma unroll
            for (int rr = 0; rr < 4; rr++) {
                const int m = m0 + mw + mt * 16 + quad * 4 + rr;
                out[(size_t)m * DMODEL + f0 + nw + nt * 16 + l15] =
                    acc[0][mt][nt][rr] + bias_v[nt];
            }
}

extern "C" void kernel_launch(void* const* d_in, const int* in_sizes, int n_in,
                              void* d_out, int out_size, void* d_ws, size_t ws_size,
                              hipStream_t stream) {
    const float* x  = (const float*)d_in[0];
    const float* wq = (const float*)d_in[1];
    const float* wo = (const float*)d_in[2];
    const float* bo = (const float*)d_in[3];
    float* out = (float*)d_out;

    const size_t per = (size_t)BH * NSEQ * HD;   // 8,388,608 elements
    unsigned short* x_hi = (unsigned short*)d_ws;   // reused as o_bf after qkv
    unsigned short* x_lo = x_hi + per;
    unsigned short* q_bf = x_lo + per;
    unsigned short* k_bf = q_bf + per;
    unsigned short* v_th = k_bf + per;
    unsigned short* wq_bf = v_th + per;                   // 786,432 els
    unsigned short* wo_bf = wq_bf + (size_t)F3 * DMODEL;  // 262,144 els (~82 MiB total)
    unsigned short* o_bf = x_hi;   // x dead after qkv

    split_kernel<<<dim3((int)(per / 1024)), 256, 0, stream>>>(x, x_hi, x_lo);
    cvt_kernel<<<dim3(F3 * DMODEL / 1024), 256, 0, stream>>>(wq, wq_bf);
    cvt_kernel<<<dim3(DMODEL * DMODEL / 1024), 256, 0, stream>>>(wo, wo_bf);
    qkv_mfma_kernel<<<dim3(NTOK / 128, F3 / 256), 256, 0, stream>>>(
        x_hi, x_lo, wq_bf, q_bf, k_bf, v_th);
    attn_kernel<<<dim3(BH, 8), 256, 0, stream>>>(
        q_bf, k_bf, v_th, o_bf);
    proj_mfma_kernel<<<dim3(NTOK / 128, DMODEL / 128), 256, 0, stream>>>(
        o_bf, wo_bf, bo, out);
}

// Round 6
// 250.468 us; speedup vs baseline: 1.1312x; 1.0921x over previous
//
#include <hip/hip_runtime.h>
#include <math.h>

#define NH 8
#define HD 64
#define NSEQ 1024
#define DMODEL 512
#define F3 1536
#define NTOK 16384
#define BH 128    // (B*T)*NH = 16*8
#define KVP 72    // attn K/V LDS pitch (bf16)
#define TP 136    // qkv epilogue transpose pitch (bf16)
#define QSCALE 0.1803368867f  // 0.125 * log2(e), folded into q; p = exp2(s')

typedef __attribute__((ext_vector_type(8))) short bf16x8;
typedef __attribute__((ext_vector_type(4))) float f32x4;
typedef __attribute__((ext_vector_type(16))) float f32x16;
typedef __attribute__((ext_vector_type(4))) unsigned int u32x4;
#define MFMA16(a, b, c) __builtin_amdgcn_mfma_f32_16x16x32_bf16(a, b, c, 0, 0, 0)
#define MFMA32(a, b, c) __builtin_amdgcn_mfma_f32_32x32x16_bf16(a, b, c, 0, 0, 0)

__device__ __forceinline__ float freq_of(int j) {
    return 3.14159265358979323846f * (1.0f + (float)j * (127.0f / 15.0f));
}
__device__ __forceinline__ unsigned short bf16_hi(float x) {
    unsigned u = __builtin_bit_cast(unsigned, x);
    return (unsigned short)(u >> 16);   // truncation split; residual goes to lo
}
__device__ __forceinline__ unsigned short bf16_rtn(float x) {
    unsigned u = __builtin_bit_cast(unsigned, x);
    return (unsigned short)((u + 0x7FFF + ((u >> 16) & 1)) >> 16);  // round-nearest-even
}
__device__ __forceinline__ float bf16_tofloat(unsigned short h) {
    unsigned u = ((unsigned)h) << 16;
    return __builtin_bit_cast(float, u);
}
// 2-bit LDS swizzle key for row r (permutes 16-B col-groups within a 64-B row)
__device__ __forceinline__ int swz(int r) { return (r & 3) ^ ((r >> 2) & 3); }

// ---------------- Kernel 0: fp32 -> bf16 RTN single plane (weights) ----------------
__global__ __launch_bounds__(256) void cvt_kernel(
        const float* __restrict__ src, unsigned short* __restrict__ dst) {
    const int i = blockIdx.x * 256 + threadIdx.x;
    const float4 v = ((const float4*)src)[i];
    ((ushort4*)dst)[i] = make_ushort4(bf16_rtn(v.x), bf16_rtn(v.y),
                                      bf16_rtn(v.z), bf16_rtn(v.w));
}

// ---- register-staged pipelined GEMM core (generic bf16 A): 128x128, BK=32 ----
template<int PLANES, int NREP>
__device__ __forceinline__ void gemm_reg_pipe(
        const unsigned short* __restrict__ a_hi, const unsigned short* __restrict__ a_lo,
        const unsigned short* __restrict__ b_bf,
        char* lds, int m0, int f0, int t, f32x4 (&acc)[NREP][4][4]) {
    const int w = t >> 6, lane = t & 63, l15 = lane & 15, quad = lane >> 4;
    const int mw = (w & 1) * 64, nw = (w >> 1) * 64;
    const int APL = PLANES - 1;           // A planes
    const int NPL = APL + NREP;           // total planes
    const int STAGE = NPL * 4096;         // elements per stage
    const int r = t >> 1;                 // 0..127: row this thread stages
    const int g0 = (t & 1) * 2;           // first of two 16-B col-groups

    uint4 regs[NPL][2];
    auto load_regs = [&](int kt) {
        const int k0 = kt * 32;
        #pragma unroll
        for (int p = 0; p < NPL; p++) {
            const unsigned short* src = (p < APL) ? (p == 0 ? a_hi : a_lo) : b_bf;
            const int row0 = (p < APL) ? m0 : (f0 + (p - APL) * 128);
            const unsigned short* g = src + (size_t)(row0 + r) * DMODEL + k0 + g0 * 8;
            regs[p][0] = *(const uint4*)g;
            regs[p][1] = *(const uint4*)(g + 8);
        }
    };
    auto store_lds = [&](int stage) {
        unsigned short* S = (unsigned short*)lds + stage * STAGE;
        const int s0 = ((g0 ^ swz(r))) * 8;
        const int s1 = (((g0 + 1) ^ swz(r))) * 8;
        #pragma unroll
        for (int p = 0; p < NPL; p++) {
            unsigned short* Sp = S + p * 4096 + r * 32;
            *(uint4*)&Sp[s0] = regs[p][0];
            *(uint4*)&Sp[s1] = regs[p][1];
        }
    };

    load_regs(0);
    store_lds(0);
    for (int kt = 0; kt < 16; kt++) {
        __syncthreads();                  // stage (kt&1) visible to all waves
        if (kt < 15) load_regs(kt + 1);   // issue next tile's global loads NOW
        const unsigned short* S = (const unsigned short*)lds + (kt & 1) * STAGE;
        bf16x8 ah[4], al[4];
        #pragma unroll
        for (int mt = 0; mt < 4; mt++) {
            const int rr = mw + mt * 16 + l15;
            const int off = rr * 32 + (quad ^ swz(rr)) * 8;
            ah[mt] = *(const bf16x8*)&S[off];
            if (APL == 2) al[mt] = *(const bf16x8*)&S[4096 + off];
        }
        #pragma unroll
        for (int nr = 0; nr < NREP; nr++) {
            bf16x8 bb[4];
            #pragma unroll
            for (int nt = 0; nt < 4; nt++) {
                const int rr = nw + nt * 16 + l15;
                bb[nt] = *(const bf16x8*)&S[(APL + nr) * 4096 + rr * 32
                                            + (quad ^ swz(rr)) * 8];
            }
            #pragma unroll
            for (int mt = 0; mt < 4; mt++)
                #pragma unroll
                for (int nt = 0; nt < 4; nt++) {
                    acc[nr][mt][nt] = MFMA16(ah[mt], bb[nt], acc[nr][mt][nt]);
                    if (APL == 2) acc[nr][mt][nt] = MFMA16(al[mt], bb[nt], acc[nr][mt][nt]);
                }
        }
        if (kt < 15) store_lds((kt + 1) & 1);  // vmcnt wait lands here, post-MFMA
    }
    __syncthreads();                      // LDS free for epilogue reuse
}

// ---- qkv pipe: fp32 A split to {hi,lo} bf16 planes IN-REGISTER at store time ----
// x_hi/x_lo planes are byte-identical to fp32 x, so reading fp32 directly costs
// the same HBM traffic and deletes the standalone split kernel (+its 67 MB).
// regs: A = 16 fp32 (4 uint4, same 16 VGPR as 2 bf16 planes); B = 2 planes.
// Conversion happens in store_lds, after compute(kt), where vmcnt already waits.
__device__ __forceinline__ void gemm_pipe_qkv(
        const float* __restrict__ x, const unsigned short* __restrict__ b_bf,
        char* lds, int m0, int f0, int t, f32x4 (&acc)[2][4][4]) {
    const int w = t >> 6, lane = t & 63, l15 = lane & 15, quad = lane >> 4;
    const int mw = (w & 1) * 64, nw = (w >> 1) * 64;
    const int STAGE = 4 * 4096;           // planes: 0=A_hi 1=A_lo 2=B(f0) 3=B(f0+128)
    const int r = t >> 1;
    const int g0 = (t & 1) * 2;

    float4 af[4];                         // 16 fp32 of A row r, cols k0+g0*8..+16
    uint4 bregs[2][2];
    auto load_regs = [&](int kt) {
        const int k0 = kt * 32;
        const float* gA = x + (size_t)(m0 + r) * DMODEL + k0 + g0 * 8;
        #pragma unroll
        for (int i = 0; i < 4; i++) af[i] = ((const float4*)gA)[i];
        #pragma unroll
        for (int p = 0; p < 2; p++) {
            const unsigned short* g =
                b_bf + (size_t)(f0 + p * 128 + r) * DMODEL + k0 + g0 * 8;
            bregs[p][0] = *(const uint4*)g;
            bregs[p][1] = *(const uint4*)(g + 8);
        }
    };
    auto store_lds = [&](int stage) {
        unsigned short* S = (unsigned short*)lds + stage * STAGE;
        const int s0 = ((g0 ^ swz(r))) * 8;
        const int s1 = (((g0 + 1) ^ swz(r))) * 8;
        // split 8 floats -> one uint4 of hi-bf16 and one of lo-bf16
        auto cvt8 = [](const float4 a, const float4 b, uint4& hq, uint4& lq) {
            const float f[8] = {a.x, a.y, a.z, a.w, b.x, b.y, b.z, b.w};
            unsigned hw[4], lw[4];
            #pragma unroll
            for (int j = 0; j < 4; j++) {
                const unsigned u0 = __builtin_bit_cast(unsigned, f[2 * j]);
                const unsigned u1 = __builtin_bit_cast(unsigned, f[2 * j + 1]);
                const float r0 = f[2 * j]     - __builtin_bit_cast(float, u0 & 0xFFFF0000u);
                const float r1 = f[2 * j + 1] - __builtin_bit_cast(float, u1 & 0xFFFF0000u);
                hw[j] = (u0 >> 16) | (u1 & 0xFFFF0000u);
                lw[j] = (__builtin_bit_cast(unsigned, r0) >> 16)
                      | (__builtin_bit_cast(unsigned, r1) & 0xFFFF0000u);
            }
            hq = make_uint4(hw[0], hw[1], hw[2], hw[3]);
            lq = make_uint4(lw[0], lw[1], lw[2], lw[3]);
        };
        uint4 h0, l0, h1, l1;
        cvt8(af[0], af[1], h0, l0);
        cvt8(af[2], af[3], h1, l1);
        unsigned short* Sh = S + r * 32;
        unsigned short* Sl = S + 4096 + r * 32;
        *(uint4*)&Sh[s0] = h0; *(uint4*)&Sh[s1] = h1;
        *(uint4*)&Sl[s0] = l0; *(uint4*)&Sl[s1] = l1;
        #pragma unroll
        for (int p = 0; p < 2; p++) {
            unsigned short* Sp = S + (2 + p) * 4096 + r * 32;
            *(uint4*)&Sp[s0] = bregs[p][0];
            *(uint4*)&Sp[s1] = bregs[p][1];
        }
    };

    load_regs(0);
    store_lds(0);
    for (int kt = 0; kt < 16; kt++) {
        __syncthreads();
        if (kt < 15) load_regs(kt + 1);
        const unsigned short* S = (const unsigned short*)lds + (kt & 1) * STAGE;
        bf16x8 ah[4], al[4];
        #pragma unroll
        for (int mt = 0; mt < 4; mt++) {
            const int rr = mw + mt * 16 + l15;
            const int off = rr * 32 + (quad ^ swz(rr)) * 8;
            ah[mt] = *(const bf16x8*)&S[off];
            al[mt] = *(const bf16x8*)&S[4096 + off];
        }
        #pragma unroll
        for (int nr = 0; nr < 2; nr++) {
            bf16x8 bb[4];
            #pragma unroll
            for (int nt = 0; nt < 4; nt++) {
                const int rr = nw + nt * 16 + l15;
                bb[nt] = *(const bf16x8*)&S[(2 + nr) * 4096 + rr * 32
                                            + (quad ^ swz(rr)) * 8];
            }
            #pragma unroll
            for (int mt = 0; mt < 4; mt++)
                #pragma unroll
                for (int nt = 0; nt < 4; nt++) {
                    acc[nr][mt][nt] = MFMA16(ah[mt], bb[nt], acc[nr][mt][nt]);
                    acc[nr][mt][nt] = MFMA16(al[mt], bb[nt], acc[nr][mt][nt]);
                }
        }
        if (kt < 15) store_lds((kt + 1) & 1);
    }
    __syncthreads();
}

// ---------------- Kernel 1: QKV GEMM + RoPE (128x256 tile, NREP=2, fused split) ----
__global__ __launch_bounds__(256, 2) void qkv_mfma_kernel(
        const float* __restrict__ x, const unsigned short* __restrict__ wq_bf,
        unsigned short* __restrict__ q_bf, unsigned short* __restrict__ k_bf,
        unsigned short* __restrict__ v_th) {
    __shared__ __align__(16) char lds[65536 + 4608];   // 2x32KB stages (+T alias) + tables
    unsigned short* T = (unsigned short*)lds;          // 128 x TP transpose buffer
    float* t_cy = (float*)(lds + 65536);               // [4][16]
    float* t_sy = t_cy + 64;
    float* t_cx = t_sy + 64;                           // [32][16]
    float* t_sx = t_cx + 512;

    const int m0 = blockIdx.x * 128;
    const int f0 = blockIdx.y * 256;
    const int t = threadIdx.x;
    const int w = t >> 6, lane = t & 63, l15 = lane & 15, quad = lane >> 4;
    const int mw = (w & 1) * 64, nw = (w >> 1) * 64;
    const int sel = f0 >> 9;                // 0=q,1=k,2=v (same for both subtiles)
    const int bt = m0 >> 10;
    const int n0 = m0 & 1023;

    if (sel != 2) {
        for (int idx = t; idx < 576; idx += 256) {
            if (idx < 64) {
                const int yi = idx >> 4, j = idx & 15;
                const float pos = -1.0f + (float)((n0 >> 5) + yi) * (2.0f / 31.0f);
                float sv, cv; sincosf(pos * freq_of(j), &sv, &cv);
                t_sy[idx] = sv; t_cy[idx] = cv;
            } else {
                const int k2 = idx - 64, xi = k2 >> 4, j = k2 & 15;
                const float pos = -1.0f + (float)xi * (2.0f / 31.0f);
                float sv, cv; sincosf(pos * freq_of(j), &sv, &cv);
                t_sx[k2] = sv; t_cx[k2] = cv;
            }
        }
    }
    __syncthreads();

    f32x4 acc[2][4][4];
    #pragma unroll
    for (int nr = 0; nr < 2; nr++)
        #pragma unroll
        for (int mt = 0; mt < 4; mt++)
            #pragma unroll
            for (int nt = 0; nt < 4; nt++) acc[nr][mt][nt] = (f32x4){0.f, 0.f, 0.f, 0.f};

    gemm_pipe_qkv(x, wq_bf, lds, m0, f0, t, acc);

    #pragma unroll
    for (int nr = 0; nr < 2; nr++) {
        const int fs = f0 + nr * 128;
        // rope in place (q,k); q additionally scaled by QSCALE so attn uses exp2
        if (sel != 2) {
            const float post = (sel == 0) ? QSCALE : 1.0f;
            #pragma unroll
            for (int mt = 0; mt < 4; mt++)
                #pragma unroll
                for (int nt = 0; nt < 4; nt++)
                    #pragma unroll
                    for (int rr = 0; rr < 4; rr++) {
                        const int ml = mw + mt * 16 + quad * 4 + rr;
                        const int dd = (nw + nt * 16 + l15) & 63;
                        const int j0 = (dd & 31) >> 1;
                        float c, s;
                        if (dd < 32) { c = t_cy[(ml >> 5) * 16 + j0]; s = t_sy[(ml >> 5) * 16 + j0]; }
                        else         { c = t_cx[(ml & 31) * 16 + j0]; s = t_sx[(ml & 31) * 16 + j0]; }
                        const float v = acc[nr][mt][nt][rr];
                        const float pv = __shfl_xor(v, 1);
                        acc[nr][mt][nt][rr] =
                            ((l15 & 1) ? (v * c + pv * s) : (v * c - pv * s)) * post;
                    }
        }

        // single RTN pass through T; v transposed, q/k row-major
        if (sel == 2) {
            #pragma unroll
            for (int mt = 0; mt < 4; mt++)
                #pragma unroll
                for (int nt = 0; nt < 4; nt++) {
                    const int fl = nw + nt * 16 + l15;
                    const int mlb = mw + mt * 16 + quad * 4;
                    ushort4 pk = make_ushort4(
                        bf16_rtn(acc[nr][mt][nt][0]), bf16_rtn(acc[nr][mt][nt][1]),
                        bf16_rtn(acc[nr][mt][nt][2]), bf16_rtn(acc[nr][mt][nt][3]));
                    *(ushort4*)&T[fl * TP + mlb] = pk;
                }
        } else {
            #pragma unroll
            for (int mt = 0; mt < 4; mt++)
                #pragma unroll
                for (int nt = 0; nt < 4; nt++)
                    #pragma unroll
                    for (int rr = 0; rr < 4; rr++) {
                        const int ml = mw + mt * 16 + quad * 4 + rr;
                        const int fl = nw + nt * 16 + l15;
                        T[ml * TP + fl] = bf16_rtn(acc[nr][mt][nt][rr]);
                    }
        }
        __syncthreads();
        if (sel == 2) {
            #pragma unroll
            for (int p = 0; p < 8; p++) {
                const int idx = p * 256 + t;
                const int fl = idx >> 4, g8 = (idx & 15) * 8;
                const int head = ((fs + fl) >> 6) & 7;
                *(uint4*)(v_th + ((size_t)(bt * NH + head) * HD + ((fs + fl) & 63)) * NSEQ
                          + n0 + g8) = *(const uint4*)&T[fl * TP + g8];
            }
        } else {
            unsigned short* dst = (sel == 0) ? q_bf : k_bf;
            #pragma unroll
            for (int p = 0; p < 8; p++) {
                const int idx = p * 256 + t;
                const int ml = idx >> 4, g8 = (idx & 15) * 8;
                const int head = ((fs + g8) >> 6) & 7;
                *(uint4*)(dst + ((size_t)(bt * NH + head) * NSEQ + n0 + ml) * HD
                          + ((fs + g8) & 63)) = *(const uint4*)&T[ml * TP + g8];
            }
        }
        __syncthreads();
    }
}

// ---------------- Kernel 2: flash attention (round-3 verbatim; 3 blocks/CU) ----
// S^T = mfma32(K, Q): lane owns one q-row (lane&31), 16 k-cols (crow(r,hi)).
// p = exp2(s) -> v_cvt_pk_bf16_f32 pairs -> v_permlane32_swap builds PV A-frags
// entirely in registers. Row-sum l via ones-B MFMA. K/V double-buffered through
// registers. (bh, qt) grid pins the 8 K/V-sharing blocks to one XCD.
// NOTE: bounds must stay (256,3): at 4 blocks/CU the per-XCD concurrent K/V
// working set hits 4 MB = L2 size and FETCH triples (round-5 regression).
__global__ __launch_bounds__(256, 3) void attn_kernel(
        const unsigned short* __restrict__ q_bf, const unsigned short* __restrict__ k_bf,
        const unsigned short* __restrict__ v_th,
        unsigned short* __restrict__ o_bf) {
    __shared__ unsigned short Ks[2][64 * KVP];  // K tile [n][d], double-buffered
    __shared__ unsigned short Vs[2][64 * KVP];  // V^T tile [d][n], double-buffered

    const int bh = blockIdx.x;     // fastest dim -> XCD = bh & 7 for all 8 qt blocks
    const int qt = blockIdx.y;     // 0..7
    const int t = threadIdx.x;
    const int w = t >> 6;
    const int lane = t & 63;
    const int l31 = lane & 31;
    const int hi = lane >> 5;

    const size_t bh_nd = (size_t)bh * NSEQ * HD;
    const size_t bh_dn = (size_t)bh * HD * NSEQ;

    bf16x8 qfB[4];
    {
        const size_t rbase = bh_nd + (size_t)(qt * 128 + w * 32 + l31) * HD + hi * 8;
        #pragma unroll
        for (int ds = 0; ds < 4; ds++)
            qfB[ds] = *(const bf16x8*)(q_bf + rbase + ds * 16);
    }

    uint4 kr[2], vr[2];
    auto load_kv = [&](int kt) {
        #pragma unroll
        for (int p = 0; p < 2; p++) {
            const int cc = t + p * 256;
            const int r = cc >> 3, off8 = (cc & 7) * 8;
            kr[p] = *(const uint4*)(k_bf + bh_nd + (size_t)(kt * 64 + r) * HD + off8);
            vr[p] = *(const uint4*)(v_th + bh_dn + (size_t)r * NSEQ + kt * 64 + off8);
        }
    };
    auto store_kv = [&](int st) {
        #pragma unroll
        for (int p = 0; p < 2; p++) {
            const int cc = t + p * 256;
            const int r = cc >> 3, off8 = (cc & 7) * 8;
            *(uint4*)&Ks[st][r * KVP + off8] = kr[p];
            *(uint4*)&Vs[st][r * KVP + off8] = vr[p];
        }
    };

    const bf16x8 ones = {(short)0x3F80, (short)0x3F80, (short)0x3F80, (short)0x3F80,
                         (short)0x3F80, (short)0x3F80, (short)0x3F80, (short)0x3F80};

    f32x16 o_acc[2], l_acc;
    #pragma unroll
    for (int i = 0; i < 16; i++) {
        o_acc[0][i] = 0.f; o_acc[1][i] = 0.f; l_acc[i] = 0.f;
    }

    load_kv(0);
    store_kv(0);
    for (int kt = 0; kt < 16; kt++) {
        __syncthreads();                  // stage (kt&1) visible
        if (kt < 15) load_kv(kt + 1);     // prefetch next tile into VGPRs
        const unsigned short* K = Ks[kt & 1];
        const unsigned short* V = Vs[kt & 1];

        #pragma unroll
        for (int nt2 = 0; nt2 < 2; nt2++) {
            // ---- S^T = K · Q^T over d=64 (4 chained K=16 MFMAs) ----
            f32x16 s;
            #pragma unroll
            for (int i = 0; i < 16; i++) s[i] = 0.f;
            #pragma unroll
            for (int ds = 0; ds < 4; ds++) {
                const bf16x8 kb =
                    *(const bf16x8*)&K[(nt2 * 32 + l31) * KVP + ds * 16 + hi * 8];
                s = MFMA32(kb, qfB[ds], s);
            }

            // ---- p = exp2(s); pack pairs to bf16 words ----
            unsigned wv[8];
            #pragma unroll
            for (int i = 0; i < 8; i++) {
                const float p0 = exp2f(s[2 * i]);
                const float p1 = exp2f(s[2 * i + 1]);
                asm("v_cvt_pk_bf16_f32 %0, %1, %2" : "=v"(wv[i]) : "v"(p0), "v"(p1));
            }
            // ---- exchange halves: vdst.hi <-> vsrc.lo (first operand = lower-k word)
            asm volatile("v_permlane32_swap_b32 %0, %1" : "+v"(wv[0]), "+v"(wv[2]));
            asm volatile("v_permlane32_swap_b32 %0, %1" : "+v"(wv[1]), "+v"(wv[3]));
            asm volatile("v_permlane32_swap_b32 %0, %1" : "+v"(wv[4]), "+v"(wv[6]));
            asm volatile("v_permlane32_swap_b32 %0, %1" : "+v"(wv[5]), "+v"(wv[7]));

            // ---- O += P·V, l += P·1 (P entirely in registers) ----
            #pragma unroll
            for (int k2 = 0; k2 < 2; k2++) {
                const u32x4 paw = {wv[k2 * 4 + 0], wv[k2 * 4 + 1],
                                   wv[k2 * 4 + 2], wv[k2 * 4 + 3]};
                const bf16x8 pa = __builtin_bit_cast(bf16x8, paw);
                const int kstep = nt2 * 2 + k2;
                l_acc = MFMA32(pa, ones, l_acc);
                #pragma unroll
                for (int dt = 0; dt < 2; dt++) {
                    const bf16x8 vb =
                        *(const bf16x8*)&V[(dt * 32 + l31) * KVP + kstep * 16 + hi * 8];
                    o_acc[dt] = MFMA32(pa, vb, o_acc[dt]);
                }
            }
        }
        if (kt < 15) store_kv((kt + 1) & 1);  // vmcnt wait lands post-MFMA
    }

    // ---- epilogue: normalize by l; LDS bounce -> full-128B-line uint4 stores ----
    __syncthreads();                       // all waves done reading Ks/Vs
    unsigned short* Osh = &Ks[0][0];       // 128 rows x KVP pitch = 9216 els, exact fit
    #pragma unroll
    for (int r = 0; r < 16; r++) {
        const float inv = 1.0f / l_acc[r];
        const int row = w * 32 + (r & 3) + 8 * (r >> 2) + 4 * hi;
        #pragma unroll
        for (int dt = 0; dt < 2; dt++)
            Osh[row * KVP + dt * 32 + l31] = bf16_rtn(o_acc[dt][r] * inv);
    }
    __syncthreads();
    const int btq = bh >> 3, head = bh & 7;
    #pragma unroll
    for (int p = 0; p < 4; p++) {
        const int idx = p * 256 + t;
        const int row = idx >> 3, g8 = (idx & 7) * 8;
        *(uint4*)(o_bf + ((size_t)(btq * NSEQ + qt * 128 + row)) * DMODEL
                  + head * HD + g8) = *(const uint4*)&Osh[row * KVP + g8];
    }
}

// ---------------- Kernel 3: output projection (2-plane, pipelined) ----------------
__global__ __launch_bounds__(256, 3) void proj_mfma_kernel(
        const unsigned short* __restrict__ o_bf,
        const unsigned short* __restrict__ wo_bf,
        const float* __restrict__ b_out, float* __restrict__ out) {
    __shared__ __align__(16) char lds[32768];   // 2 x 16KB stages

    const int m0 = blockIdx.x * 128;
    const int f0 = blockIdx.y * 128;
    const int t = threadIdx.x;
    const int w = t >> 6, lane = t & 63, l15 = lane & 15, quad = lane >> 4;
    const int mw = (w & 1) * 64, nw = (w >> 1) * 64;

    f32x4 acc[1][4][4];
    #pragma unroll
    for (int mt = 0; mt < 4; mt++)
        #pragma unroll
        for (int nt = 0; nt < 4; nt++) acc[0][mt][nt] = (f32x4){0.f, 0.f, 0.f, 0.f};

    gemm_reg_pipe<2, 1>(o_bf, o_bf, wo_bf, lds, m0, f0, t, acc);

    float bias_v[4];
    #pragma unroll
    for (int nt = 0; nt < 4; nt++) bias_v[nt] = b_out[f0 + nw + nt * 16 + l15];
    #pragma unroll
    for (int mt = 0; mt < 4; mt++)
        #pragma unroll
        for (int nt = 0; nt < 4; nt++)
            #pragma unroll
            for (int rr = 0; rr < 4; rr++) {
                const int m = m0 + mw + mt * 16 + quad * 4 + rr;
                out[(size_t)m * DMODEL + f0 + nw + nt * 16 + l15] =
                    acc[0][mt][nt][rr] + bias_v[nt];
            }
}

extern "C" void kernel_launch(void* const* d_in, const int* in_sizes, int n_in,
                              void* d_out, int out_size, void* d_ws, size_t ws_size,
                              hipStream_t stream) {
    const float* x  = (const float*)d_in[0];
    const float* wq = (const float*)d_in[1];
    const float* wo = (const float*)d_in[2];
    const float* bo = (const float*)d_in[3];
    float* out = (float*)d_out;

    const size_t per = (size_t)BH * NSEQ * HD;   // 8,388,608 elements
    unsigned short* o_bf = (unsigned short*)d_ws;
    unsigned short* q_bf = o_bf + per;
    unsigned short* k_bf = q_bf + per;
    unsigned short* v_th = k_bf + per;
    unsigned short* wq_bf = v_th + per;                   // 786,432 els
    unsigned short* wo_bf = wq_bf + (size_t)F3 * DMODEL;  // 262,144 els (~66 MiB total)

    cvt_kernel<<<dim3(F3 * DMODEL / 1024), 256, 0, stream>>>(wq, wq_bf);
    cvt_kernel<<<dim3(DMODEL * DMODEL / 1024), 256, 0, stream>>>(wo, wo_bf);
    qkv_mfma_kernel<<<dim3(NTOK / 128, F3 / 256), 256, 0, stream>>>(
        x, wq_bf, q_bf, k_bf, v_th);
    attn_kernel<<<dim3(BH, 8), 256, 0, stream>>>(
        q_bf, k_bf, v_th, o_bf);
    proj_mfma_kernel<<<dim3(NTOK / 128, DMODEL / 128), 256, 0, stream>>>(
        o_bf, wo_bf, bo, out);
}

// Round 7
// 234.280 us; speedup vs baseline: 1.2093x; 1.0691x over previous
//
#include <hip/hip_runtime.h>
#include <math.h>

#define NH 8
#define HD 64
#define NSEQ 1024
#define DMODEL 512
#define F3 1536
#define NTOK 16384
#define BH 128    // (B*T)*NH = 16*8
#define KVP 72    // attn K/V LDS pitch (bf16)
#define TP 136    // qkv epilogue transpose pitch (bf16)
#define QSCALE 0.1803368867f  // 0.125 * log2(e), folded into q; p = exp2(s')

typedef __attribute__((ext_vector_type(8))) short bf16x8;
typedef __attribute__((ext_vector_type(4))) float f32x4;
typedef __attribute__((ext_vector_type(16))) float f32x16;
typedef __attribute__((ext_vector_type(4))) unsigned int u32x4;
#define MFMA16(a, b, c) __builtin_amdgcn_mfma_f32_16x16x32_bf16(a, b, c, 0, 0, 0)
#define MFMA32(a, b, c) __builtin_amdgcn_mfma_f32_32x32x16_bf16(a, b, c, 0, 0, 0)

__device__ __forceinline__ float freq_of(int j) {
    return 3.14159265358979323846f * (1.0f + (float)j * (127.0f / 15.0f));
}
__device__ __forceinline__ unsigned short bf16_rtn(float x) {
    unsigned u = __builtin_bit_cast(unsigned, x);
    return (unsigned short)((u + 0x7FFF + ((u >> 16) & 1)) >> 16);  // round-nearest-even
}
// 2-bit LDS swizzle key for row r (permutes 16-B col-groups within a 64-B row)
__device__ __forceinline__ int swz(int r) { return (r & 3) ^ ((r >> 2) & 3); }

// ---------------- Kernel 0: fp32 -> bf16 RTN, both weight tensors ----------------
__global__ __launch_bounds__(256) void cvt2_kernel(
        const float* __restrict__ wq, unsigned short* __restrict__ wq_bf,
        const float* __restrict__ wo, unsigned short* __restrict__ wo_bf) {
    const int b = blockIdx.x;
    const float* src;
    unsigned short* dst;
    int i;
    if (b < F3 * DMODEL / 1024) { src = wq; dst = wq_bf; i = b * 256 + threadIdx.x; }
    else { src = wo; dst = wo_bf; i = (b - F3 * DMODEL / 1024) * 256 + threadIdx.x; }
    const float4 v = ((const float4*)src)[i];
    ((ushort4*)dst)[i] = make_ushort4(bf16_rtn(v.x), bf16_rtn(v.y),
                                      bf16_rtn(v.z), bf16_rtn(v.w));
}

// ---- register-staged pipelined GEMM core (generic bf16 A): 128x(128*NREP), BK=32 ----
template<int PLANES, int NREP>
__device__ __forceinline__ void gemm_reg_pipe(
        const unsigned short* __restrict__ a_hi, const unsigned short* __restrict__ a_lo,
        const unsigned short* __restrict__ b_bf,
        char* lds, int m0, int f0, int t, f32x4 (&acc)[NREP][4][4]) {
    const int w = t >> 6, lane = t & 63, l15 = lane & 15, quad = lane >> 4;
    const int mw = (w & 1) * 64, nw = (w >> 1) * 64;
    const int APL = PLANES - 1;           // A planes
    const int NPL = APL + NREP;           // total planes
    const int STAGE = NPL * 4096;         // elements per stage
    const int r = t >> 1;                 // 0..127: row this thread stages
    const int g0 = (t & 1) * 2;           // first of two 16-B col-groups

    uint4 regs[NPL][2];
    auto load_regs = [&](int kt) {
        const int k0 = kt * 32;
        #pragma unroll
        for (int p = 0; p < NPL; p++) {
            const unsigned short* src = (p < APL) ? (p == 0 ? a_hi : a_lo) : b_bf;
            const int row0 = (p < APL) ? m0 : (f0 + (p - APL) * 128);
            const unsigned short* g = src + (size_t)(row0 + r) * DMODEL + k0 + g0 * 8;
            regs[p][0] = *(const uint4*)g;
            regs[p][1] = *(const uint4*)(g + 8);
        }
    };
    auto store_lds = [&](int stage) {
        unsigned short* S = (unsigned short*)lds + stage * STAGE;
        const int s0 = ((g0 ^ swz(r))) * 8;
        const int s1 = (((g0 + 1) ^ swz(r))) * 8;
        #pragma unroll
        for (int p = 0; p < NPL; p++) {
            unsigned short* Sp = S + p * 4096 + r * 32;
            *(uint4*)&Sp[s0] = regs[p][0];
            *(uint4*)&Sp[s1] = regs[p][1];
        }
    };

    load_regs(0);
    store_lds(0);
    for (int kt = 0; kt < 16; kt++) {
        __syncthreads();                  // stage (kt&1) visible to all waves
        if (kt < 15) load_regs(kt + 1);   // issue next tile's global loads NOW
        const unsigned short* S = (const unsigned short*)lds + (kt & 1) * STAGE;
        bf16x8 ah[4], al[4];
        #pragma unroll
        for (int mt = 0; mt < 4; mt++) {
            const int rr = mw + mt * 16 + l15;
            const int off = rr * 32 + (quad ^ swz(rr)) * 8;
            ah[mt] = *(const bf16x8*)&S[off];
            if (APL == 2) al[mt] = *(const bf16x8*)&S[4096 + off];
        }
        #pragma unroll
        for (int nr = 0; nr < NREP; nr++) {
            bf16x8 bb[4];
            #pragma unroll
            for (int nt = 0; nt < 4; nt++) {
                const int rr = nw + nt * 16 + l15;
                bb[nt] = *(const bf16x8*)&S[(APL + nr) * 4096 + rr * 32
                                            + (quad ^ swz(rr)) * 8];
            }
            #pragma unroll
            for (int mt = 0; mt < 4; mt++)
                #pragma unroll
                for (int nt = 0; nt < 4; nt++) {
                    acc[nr][mt][nt] = MFMA16(ah[mt], bb[nt], acc[nr][mt][nt]);
                    if (APL == 2) acc[nr][mt][nt] = MFMA16(al[mt], bb[nt], acc[nr][mt][nt]);
                }
        }
        if (kt < 15) store_lds((kt + 1) & 1);  // vmcnt wait lands here, post-MFMA
    }
    __syncthreads();                      // LDS free for epilogue reuse
}

// ---- qkv pipe: fp32 A split to {hi,lo} bf16 planes IN-REGISTER at store time ----
__device__ __forceinline__ void gemm_pipe_qkv(
        const float* __restrict__ x, const unsigned short* __restrict__ b_bf,
        char* lds, int m0, int f0, int t, f32x4 (&acc)[2][4][4]) {
    const int w = t >> 6, lane = t & 63, l15 = lane & 15, quad = lane >> 4;
    const int mw = (w & 1) * 64, nw = (w >> 1) * 64;
    const int STAGE = 4 * 4096;           // planes: 0=A_hi 1=A_lo 2=B(f0) 3=B(f0+128)
    const int r = t >> 1;
    const int g0 = (t & 1) * 2;

    float4 af[4];                         // 16 fp32 of A row r, cols k0+g0*8..+16
    uint4 bregs[2][2];
    auto load_regs = [&](int kt) {
        const int k0 = kt * 32;
        const float* gA = x + (size_t)(m0 + r) * DMODEL + k0 + g0 * 8;
        #pragma unroll
        for (int i = 0; i < 4; i++) af[i] = ((const float4*)gA)[i];
        #pragma unroll
        for (int p = 0; p < 2; p++) {
            const unsigned short* g =
                b_bf + (size_t)(f0 + p * 128 + r) * DMODEL + k0 + g0 * 8;
            bregs[p][0] = *(const uint4*)g;
            bregs[p][1] = *(const uint4*)(g + 8);
        }
    };
    auto store_lds = [&](int stage) {
        unsigned short* S = (unsigned short*)lds + stage * STAGE;
        const int s0 = ((g0 ^ swz(r))) * 8;
        const int s1 = (((g0 + 1) ^ swz(r))) * 8;
        auto cvt8 = [](const float4 a, const float4 b, uint4& hq, uint4& lq) {
            const float f[8] = {a.x, a.y, a.z, a.w, b.x, b.y, b.z, b.w};
            unsigned hw[4], lw[4];
            #pragma unroll
            for (int j = 0; j < 4; j++) {
                const unsigned u0 = __builtin_bit_cast(unsigned, f[2 * j]);
                const unsigned u1 = __builtin_bit_cast(unsigned, f[2 * j + 1]);
                const float r0 = f[2 * j]     - __builtin_bit_cast(float, u0 & 0xFFFF0000u);
                const float r1 = f[2 * j + 1] - __builtin_bit_cast(float, u1 & 0xFFFF0000u);
                hw[j] = (u0 >> 16) | (u1 & 0xFFFF0000u);
                lw[j] = (__builtin_bit_cast(unsigned, r0) >> 16)
                      | (__builtin_bit_cast(unsigned, r1) & 0xFFFF0000u);
            }
            hq = make_uint4(hw[0], hw[1], hw[2], hw[3]);
            lq = make_uint4(lw[0], lw[1], lw[2], lw[3]);
        };
        uint4 h0, l0, h1, l1;
        cvt8(af[0], af[1], h0, l0);
        cvt8(af[2], af[3], h1, l1);
        unsigned short* Sh = S + r * 32;
        unsigned short* Sl = S + 4096 + r * 32;
        *(uint4*)&Sh[s0] = h0; *(uint4*)&Sh[s1] = h1;
        *(uint4*)&Sl[s0] = l0; *(uint4*)&Sl[s1] = l1;
        #pragma unroll
        for (int p = 0; p < 2; p++) {
            unsigned short* Sp = S + (2 + p) * 4096 + r * 32;
            *(uint4*)&Sp[s0] = bregs[p][0];
            *(uint4*)&Sp[s1] = bregs[p][1];
        }
    };

    load_regs(0);
    store_lds(0);
    for (int kt = 0; kt < 16; kt++) {
        __syncthreads();
        if (kt < 15) load_regs(kt + 1);
        const unsigned short* S = (const unsigned short*)lds + (kt & 1) * STAGE;
        bf16x8 ah[4], al[4];
        #pragma unroll
        for (int mt = 0; mt < 4; mt++) {
            const int rr = mw + mt * 16 + l15;
            const int off = rr * 32 + (quad ^ swz(rr)) * 8;
            ah[mt] = *(const bf16x8*)&S[off];
            al[mt] = *(const bf16x8*)&S[4096 + off];
        }
        #pragma unroll
        for (int nr = 0; nr < 2; nr++) {
            bf16x8 bb[4];
            #pragma unroll
            for (int nt = 0; nt < 4; nt++) {
                const int rr = nw + nt * 16 + l15;
                bb[nt] = *(const bf16x8*)&S[(2 + nr) * 4096 + rr * 32
                                            + (quad ^ swz(rr)) * 8];
            }
            #pragma unroll
            for (int mt = 0; mt < 4; mt++)
                #pragma unroll
                for (int nt = 0; nt < 4; nt++) {
                    acc[nr][mt][nt] = MFMA16(ah[mt], bb[nt], acc[nr][mt][nt]);
                    acc[nr][mt][nt] = MFMA16(al[mt], bb[nt], acc[nr][mt][nt]);
                }
        }
        if (kt < 15) store_lds((kt + 1) & 1);
    }
    __syncthreads();
}

// ---------------- Kernel 1: QKV GEMM + RoPE (128x256 tile, NREP=2, fused split) ----
__global__ __launch_bounds__(256, 2) void qkv_mfma_kernel(
        const float* __restrict__ x, const unsigned short* __restrict__ wq_bf,
        unsigned short* __restrict__ q_bf, unsigned short* __restrict__ k_bf,
        unsigned short* __restrict__ v_th) {
    __shared__ __align__(16) char lds[65536 + 4608];   // 2x32KB stages (+T alias) + tables
    unsigned short* T = (unsigned short*)lds;          // 128 x TP transpose buffer
    float* t_cy = (float*)(lds + 65536);               // [4][16]
    float* t_sy = t_cy + 64;
    float* t_cx = t_sy + 64;                           // [32][16]
    float* t_sx = t_cx + 512;

    const int m0 = blockIdx.x * 128;
    const int f0 = blockIdx.y * 256;
    const int t = threadIdx.x;
    const int w = t >> 6, lane = t & 63, l15 = lane & 15, quad = lane >> 4;
    const int mw = (w & 1) * 64, nw = (w >> 1) * 64;
    const int sel = f0 >> 9;                // 0=q,1=k,2=v (same for both subtiles)
    const int bt = m0 >> 10;
    const int n0 = m0 & 1023;

    if (sel != 2) {
        for (int idx = t; idx < 576; idx += 256) {
            if (idx < 64) {
                const int yi = idx >> 4, j = idx & 15;
                const float pos = -1.0f + (float)((n0 >> 5) + yi) * (2.0f / 31.0f);
                float sv, cv; sincosf(pos * freq_of(j), &sv, &cv);
                t_sy[idx] = sv; t_cy[idx] = cv;
            } else {
                const int k2 = idx - 64, xi = k2 >> 4, j = k2 & 15;
                const float pos = -1.0f + (float)xi * (2.0f / 31.0f);
                float sv, cv; sincosf(pos * freq_of(j), &sv, &cv);
                t_sx[k2] = sv; t_cx[k2] = cv;
            }
        }
    }
    __syncthreads();

    f32x4 acc[2][4][4];
    #pragma unroll
    for (int nr = 0; nr < 2; nr++)
        #pragma unroll
        for (int mt = 0; mt < 4; mt++)
            #pragma unroll
            for (int nt = 0; nt < 4; nt++) acc[nr][mt][nt] = (f32x4){0.f, 0.f, 0.f, 0.f};

    gemm_pipe_qkv(x, wq_bf, lds, m0, f0, t, acc);

    #pragma unroll
    for (int nr = 0; nr < 2; nr++) {
        const int fs = f0 + nr * 128;
        if (sel != 2) {
            const float post = (sel == 0) ? QSCALE : 1.0f;
            #pragma unroll
            for (int mt = 0; mt < 4; mt++)
                #pragma unroll
                for (int nt = 0; nt < 4; nt++)
                    #pragma unroll
                    for (int rr = 0; rr < 4; rr++) {
                        const int ml = mw + mt * 16 + quad * 4 + rr;
                        const int dd = (nw + nt * 16 + l15) & 63;
                        const int j0 = (dd & 31) >> 1;
                        float c, s;
                        if (dd < 32) { c = t_cy[(ml >> 5) * 16 + j0]; s = t_sy[(ml >> 5) * 16 + j0]; }
                        else         { c = t_cx[(ml & 31) * 16 + j0]; s = t_sx[(ml & 31) * 16 + j0]; }
                        const float v = acc[nr][mt][nt][rr];
                        const float pv = __shfl_xor(v, 1);
                        acc[nr][mt][nt][rr] =
                            ((l15 & 1) ? (v * c + pv * s) : (v * c - pv * s)) * post;
                    }
        }

        if (sel == 2) {
            #pragma unroll
            for (int mt = 0; mt < 4; mt++)
                #pragma unroll
                for (int nt = 0; nt < 4; nt++) {
                    const int fl = nw + nt * 16 + l15;
                    const int mlb = mw + mt * 16 + quad * 4;
                    ushort4 pk = make_ushort4(
                        bf16_rtn(acc[nr][mt][nt][0]), bf16_rtn(acc[nr][mt][nt][1]),
                        bf16_rtn(acc[nr][mt][nt][2]), bf16_rtn(acc[nr][mt][nt][3]));
                    *(ushort4*)&T[fl * TP + mlb] = pk;
                }
        } else {
            #pragma unroll
            for (int mt = 0; mt < 4; mt++)
                #pragma unroll
                for (int nt = 0; nt < 4; nt++)
                    #pragma unroll
                    for (int rr = 0; rr < 4; rr++) {
                        const int ml = mw + mt * 16 + quad * 4 + rr;
                        const int fl = nw + nt * 16 + l15;
                        T[ml * TP + fl] = bf16_rtn(acc[nr][mt][nt][rr]);
                    }
        }
        __syncthreads();
        if (sel == 2) {
            #pragma unroll
            for (int p = 0; p < 8; p++) {
                const int idx = p * 256 + t;
                const int fl = idx >> 4, g8 = (idx & 15) * 8;
                const int head = ((fs + fl) >> 6) & 7;
                *(uint4*)(v_th + ((size_t)(bt * NH + head) * HD + ((fs + fl) & 63)) * NSEQ
                          + n0 + g8) = *(const uint4*)&T[fl * TP + g8];
            }
        } else {
            unsigned short* dst = (sel == 0) ? q_bf : k_bf;
            #pragma unroll
            for (int p = 0; p < 8; p++) {
                const int idx = p * 256 + t;
                const int ml = idx >> 4, g8 = (idx & 15) * 8;
                const int head = ((fs + g8) >> 6) & 7;
                *(uint4*)(dst + ((size_t)(bt * NH + head) * NSEQ + n0 + ml) * HD
                          + ((fs + g8) & 63)) = *(const uint4*)&T[ml * TP + g8];
            }
        }
        __syncthreads();
    }
}

// ---------------- Kernel 2: flash attention, QBLK=256 (2 mf sub-tiles/wave) ----
// Same swapped-QK^T 32x32 in-register-P structure as round 3, but each block
// now owns 256 q-rows: K frags shared across both mf chains, V frags shared
// across both mf PV chains, barriers amortized 2x, total K/V L2 traffic halved
// (512 blocks x 256 KB). Grid (bh, qt): 8->4 qt, all K/V sharers on one XCD.
// 2 blocks/CU (VGPR ~190); per-XCD KV working set 4 MB with halved streaming.
__global__ __launch_bounds__(256, 2) void attn_kernel(
        const unsigned short* __restrict__ q_bf, const unsigned short* __restrict__ k_bf,
        const unsigned short* __restrict__ v_th,
        unsigned short* __restrict__ o_bf) {
    __shared__ unsigned short Ks[2][64 * KVP];  // K tile [n][d], double-buffered
    __shared__ unsigned short Vs[2][64 * KVP];  // V^T tile [d][n], double-buffered

    const int bh = blockIdx.x;     // fastest dim -> XCD = bh & 7 for all 4 qt blocks
    const int qt = blockIdx.y;     // 0..3
    const int t = threadIdx.x;
    const int w = t >> 6;
    const int lane = t & 63;
    const int l31 = lane & 31;
    const int hi = lane >> 5;

    const size_t bh_nd = (size_t)bh * NSEQ * HD;
    const size_t bh_dn = (size_t)bh * HD * NSEQ;

    // Q B-fragments for two 32-row sub-tiles: qrow = qt*256 + w*64 + mf*32 + l31
    bf16x8 qfB[2][4];
    #pragma unroll
    for (int mf = 0; mf < 2; mf++) {
        const size_t rbase =
            bh_nd + (size_t)(qt * 256 + w * 64 + mf * 32 + l31) * HD + hi * 8;
        #pragma unroll
        for (int ds = 0; ds < 4; ds++)
            qfB[mf][ds] = *(const bf16x8*)(q_bf + rbase + ds * 16);
    }

    uint4 kr[2], vr[2];
    auto load_kv = [&](int kt) {
        #pragma unroll
        for (int p = 0; p < 2; p++) {
            const int cc = t + p * 256;
            const int r = cc >> 3, off8 = (cc & 7) * 8;
            kr[p] = *(const uint4*)(k_bf + bh_nd + (size_t)(kt * 64 + r) * HD + off8);
            vr[p] = *(const uint4*)(v_th + bh_dn + (size_t)r * NSEQ + kt * 64 + off8);
        }
    };
    auto store_kv = [&](int st) {
        #pragma unroll
        for (int p = 0; p < 2; p++) {
            const int cc = t + p * 256;
            const int r = cc >> 3, off8 = (cc & 7) * 8;
            *(uint4*)&Ks[st][r * KVP + off8] = kr[p];
            *(uint4*)&Vs[st][r * KVP + off8] = vr[p];
        }
    };

    const bf16x8 ones = {(short)0x3F80, (short)0x3F80, (short)0x3F80, (short)0x3F80,
                         (short)0x3F80, (short)0x3F80, (short)0x3F80, (short)0x3F80};

    f32x16 o_acc[2][2], l_acc[2];
    #pragma unroll
    for (int i = 0; i < 16; i++) {
        o_acc[0][0][i] = 0.f; o_acc[0][1][i] = 0.f;
        o_acc[1][0][i] = 0.f; o_acc[1][1][i] = 0.f;
        l_acc[0][i] = 0.f; l_acc[1][i] = 0.f;
    }

    load_kv(0);
    store_kv(0);
    for (int kt = 0; kt < 16; kt++) {
        __syncthreads();                  // stage (kt&1) visible
        if (kt < 15) load_kv(kt + 1);     // prefetch next tile into VGPRs
        const unsigned short* K = Ks[kt & 1];
        const unsigned short* V = Vs[kt & 1];

        #pragma unroll
        for (int nt2 = 0; nt2 < 2; nt2++) {
            // ---- K fragments, shared by both mf chains ----
            bf16x8 kb[4];
            #pragma unroll
            for (int ds = 0; ds < 4; ds++)
                kb[ds] = *(const bf16x8*)&K[(nt2 * 32 + l31) * KVP + ds * 16 + hi * 8];

            // ---- S^T, softmax, pack: one P A-frag pair per mf ----
            u32x4 paw[2][2];
            #pragma unroll
            for (int mf = 0; mf < 2; mf++) {
                f32x16 s;
                #pragma unroll
                for (int i = 0; i < 16; i++) s[i] = 0.f;
                #pragma unroll
                for (int ds = 0; ds < 4; ds++) s = MFMA32(kb[ds], qfB[mf][ds], s);

                unsigned wv[8];
                #pragma unroll
                for (int i = 0; i < 8; i++) {
                    const float p0 = exp2f(s[2 * i]);
                    const float p1 = exp2f(s[2 * i + 1]);
                    asm("v_cvt_pk_bf16_f32 %0, %1, %2" : "=v"(wv[i]) : "v"(p0), "v"(p1));
                }
                // exchange halves: vdst.hi <-> vsrc.lo (first operand = lower-k word)
                asm volatile("v_permlane32_swap_b32 %0, %1" : "+v"(wv[0]), "+v"(wv[2]));
                asm volatile("v_permlane32_swap_b32 %0, %1" : "+v"(wv[1]), "+v"(wv[3]));
                asm volatile("v_permlane32_swap_b32 %0, %1" : "+v"(wv[4]), "+v"(wv[6]));
                asm volatile("v_permlane32_swap_b32 %0, %1" : "+v"(wv[5]), "+v"(wv[7]));
                paw[mf][0] = (u32x4){wv[0], wv[1], wv[2], wv[3]};
                paw[mf][1] = (u32x4){wv[4], wv[5], wv[6], wv[7]};
            }

            // ---- O += P·V, l += P·1; V fragments shared by both mf ----
            #pragma unroll
            for (int k2 = 0; k2 < 2; k2++) {
                bf16x8 vb[2];
                #pragma unroll
                for (int dt = 0; dt < 2; dt++)
                    vb[dt] = *(const bf16x8*)&V[(dt * 32 + l31) * KVP
                                 + (nt2 * 2 + k2) * 16 + hi * 8];
                #pragma unroll
                for (int mf = 0; mf < 2; mf++) {
                    const bf16x8 pa = __builtin_bit_cast(bf16x8, paw[mf][k2]);
                    l_acc[mf] = MFMA32(pa, ones, l_acc[mf]);
                    #pragma unroll
                    for (int dt = 0; dt < 2; dt++)
                        o_acc[mf][dt] = MFMA32(pa, vb[dt], o_acc[mf][dt]);
                }
            }
        }
        if (kt < 15) store_kv((kt + 1) & 1);  // vmcnt wait lands post-MFMA
    }

    // ---- epilogue: normalize by l; LDS bounce -> full-128B-line uint4 stores ----
    __syncthreads();                       // all waves done reading Ks/Vs
    unsigned short* Osh = &Ks[0][0];       // 256 rows x KVP pitch = 18432 els, exact fit
    #pragma unroll
    for (int mf = 0; mf < 2; mf++)
        #pragma unroll
        for (int r = 0; r < 16; r++) {
            const float inv = 1.0f / l_acc[mf][r];
            const int row = w * 64 + mf * 32 + (r & 3) + 8 * (r >> 2) + 4 * hi;
            #pragma unroll
            for (int dt = 0; dt < 2; dt++)
                Osh[row * KVP + dt * 32 + l31] = bf16_rtn(o_acc[mf][dt][r] * inv);
        }
    __syncthreads();
    const int btq = bh >> 3, head = bh & 7;
    #pragma unroll
    for (int p = 0; p < 8; p++) {
        const int idx = p * 256 + t;
        const int row = idx >> 3, g8 = (idx & 7) * 8;
        *(uint4*)(o_bf + ((size_t)(btq * NSEQ + qt * 256 + row)) * DMODEL
                  + head * HD + g8) = *(const uint4*)&Osh[row * KVP + g8];
    }
}

// ---------------- Kernel 3: output projection (128x256, NREP=2, pipelined) ----------------
__global__ __launch_bounds__(256, 2) void proj_mfma_kernel(
        const unsigned short* __restrict__ o_bf,
        const unsigned short* __restrict__ wo_bf,
        const float* __restrict__ b_out, float* __restrict__ out) {
    __shared__ __align__(16) char lds[49152];   // 2 x 24KB stages (3 planes)

    const int m0 = blockIdx.x * 128;
    const int f0 = blockIdx.y * 256;
    const int t = threadIdx.x;
    const int w = t >> 6, lane = t & 63, l15 = lane & 15, quad = lane >> 4;
    const int mw = (w & 1) * 64, nw = (w >> 1) * 64;

    f32x4 acc[2][4][4];
    #pragma unroll
    for (int nr = 0; nr < 2; nr++)
        #pragma unroll
        for (int mt = 0; mt < 4; mt++)
            #pragma unroll
            for (int nt = 0; nt < 4; nt++) acc[nr][mt][nt] = (f32x4){0.f, 0.f, 0.f, 0.f};

    gemm_reg_pipe<2, 2>(o_bf, o_bf, wo_bf, lds, m0, f0, t, acc);

    #pragma unroll
    for (int nr = 0; nr < 2; nr++) {
        const int fs = f0 + nr * 128;
        float bias_v[4];
        #pragma unroll
        for (int nt = 0; nt < 4; nt++) bias_v[nt] = b_out[fs + nw + nt * 16 + l15];
        #pragma unroll
        for (int mt = 0; mt < 4; mt++)
            #pragma unroll
            for (int nt = 0; nt < 4; nt++)
                #pragma unroll
                for (int rr = 0; rr < 4; rr++) {
                    const int m = m0 + mw + mt * 16 + quad * 4 + rr;
                    out[(size_t)m * DMODEL + fs + nw + nt * 16 + l15] =
                        acc[nr][mt][nt][rr] + bias_v[nt];
                }
    }
}

extern "C" void kernel_launch(void* const* d_in, const int* in_sizes, int n_in,
                              void* d_out, int out_size, void* d_ws, size_t ws_size,
                              hipStream_t stream) {
    const float* x  = (const float*)d_in[0];
    const float* wq = (const float*)d_in[1];
    const float* wo = (const float*)d_in[2];
    const float* bo = (const float*)d_in[3];
    float* out = (float*)d_out;

    const size_t per = (size_t)BH * NSEQ * HD;   // 8,388,608 elements
    unsigned short* o_bf = (unsigned short*)d_ws;
    unsigned short* q_bf = o_bf + per;
    unsigned short* k_bf = q_bf + per;
    unsigned short* v_th = k_bf + per;
    unsigned short* wq_bf = v_th + per;                   // 786,432 els
    unsigned short* wo_bf = wq_bf + (size_t)F3 * DMODEL;  // 262,144 els (~66 MiB total)

    cvt2_kernel<<<dim3((F3 * DMODEL + DMODEL * DMODEL) / 1024), 256, 0, stream>>>(
        wq, wq_bf, wo, wo_bf);
    qkv_mfma_kernel<<<dim3(NTOK / 128, F3 / 256), 256, 0, stream>>>(
        x, wq_bf, q_bf, k_bf, v_th);
    attn_kernel<<<dim3(BH, 4), 256, 0, stream>>>(
        q_bf, k_bf, v_th, o_bf);
    proj_mfma_kernel<<<dim3(NTOK / 128, DMODEL / 256), 256, 0, stream>>>(
        o_bf, wo_bf, bo, out);
}

// Round 8
// 218.276 us; speedup vs baseline: 1.2980x; 1.0733x over previous
//
#include <hip/hip_runtime.h>
#include <math.h>

#define NH 8
#define HD 64
#define NSEQ 1024
#define DMODEL 512
#define F3 1536
#define NTOK 16384
#define BH 128    // (B*T)*NH = 16*8
#define KVP 72    // attn K/V LDS pitch (bf16)
#define TP 136    // qkv epilogue transpose pitch (bf16)
#define QSCALE 0.1803368867f  // 0.125 * log2(e), folded into q; p = exp2(s')

typedef __attribute__((ext_vector_type(8))) short bf16x8;
typedef __attribute__((ext_vector_type(4))) float f32x4;
typedef __attribute__((ext_vector_type(16))) float f32x16;
typedef __attribute__((ext_vector_type(4))) unsigned int u32x4;
#define MFMA16(a, b, c) __builtin_amdgcn_mfma_f32_16x16x32_bf16(a, b, c, 0, 0, 0)
#define MFMA32(a, b, c) __builtin_amdgcn_mfma_f32_32x32x16_bf16(a, b, c, 0, 0, 0)

__device__ __forceinline__ float freq_of(int j) {
    return 3.14159265358979323846f * (1.0f + (float)j * (127.0f / 15.0f));
}
__device__ __forceinline__ unsigned short bf16_rtn(float x) {
    unsigned u = __builtin_bit_cast(unsigned, x);
    return (unsigned short)((u + 0x7FFF + ((u >> 16) & 1)) >> 16);  // round-nearest-even
}
// 2-bit LDS swizzle key for row r (permutes 16-B col-groups within a 64-B row)
__device__ __forceinline__ int swz(int r) { return (r & 3) ^ ((r >> 2) & 3); }

// ---------------- Kernel 0: fp32 -> bf16 RTN, both weight tensors ----------------
__global__ __launch_bounds__(256) void cvt2_kernel(
        const float* __restrict__ wq, unsigned short* __restrict__ wq_bf,
        const float* __restrict__ wo, unsigned short* __restrict__ wo_bf) {
    const int b = blockIdx.x;
    const float* src;
    unsigned short* dst;
    int i;
    if (b < F3 * DMODEL / 1024) { src = wq; dst = wq_bf; i = b * 256 + threadIdx.x; }
    else { src = wo; dst = wo_bf; i = (b - F3 * DMODEL / 1024) * 256 + threadIdx.x; }
    const float4 v = ((const float4*)src)[i];
    ((ushort4*)dst)[i] = make_ushort4(bf16_rtn(v.x), bf16_rtn(v.y),
                                      bf16_rtn(v.z), bf16_rtn(v.w));
}

// ---- register-staged pipelined GEMM core (generic bf16 A): 128x(128*NREP), BK=32 ----
template<int PLANES, int NREP>
__device__ __forceinline__ void gemm_reg_pipe(
        const unsigned short* __restrict__ a_hi, const unsigned short* __restrict__ a_lo,
        const unsigned short* __restrict__ b_bf,
        char* lds, int m0, int f0, int t, f32x4 (&acc)[NREP][4][4]) {
    const int w = t >> 6, lane = t & 63, l15 = lane & 15, quad = lane >> 4;
    const int mw = (w & 1) * 64, nw = (w >> 1) * 64;
    const int APL = PLANES - 1;           // A planes
    const int NPL = APL + NREP;           // total planes
    const int STAGE = NPL * 4096;         // elements per stage
    const int r = t >> 1;                 // 0..127: row this thread stages
    const int g0 = (t & 1) * 2;           // first of two 16-B col-groups

    uint4 regs[NPL][2];
    auto load_regs = [&](int kt) {
        const int k0 = kt * 32;
        #pragma unroll
        for (int p = 0; p < NPL; p++) {
            const unsigned short* src = (p < APL) ? (p == 0 ? a_hi : a_lo) : b_bf;
            const int row0 = (p < APL) ? m0 : (f0 + (p - APL) * 128);
            const unsigned short* g = src + (size_t)(row0 + r) * DMODEL + k0 + g0 * 8;
            regs[p][0] = *(const uint4*)g;
            regs[p][1] = *(const uint4*)(g + 8);
        }
    };
    auto store_lds = [&](int stage) {
        unsigned short* S = (unsigned short*)lds + stage * STAGE;
        const int s0 = ((g0 ^ swz(r))) * 8;
        const int s1 = (((g0 + 1) ^ swz(r))) * 8;
        #pragma unroll
        for (int p = 0; p < NPL; p++) {
            unsigned short* Sp = S + p * 4096 + r * 32;
            *(uint4*)&Sp[s0] = regs[p][0];
            *(uint4*)&Sp[s1] = regs[p][1];
        }
    };

    load_regs(0);
    store_lds(0);
    for (int kt = 0; kt < 16; kt++) {
        __syncthreads();                  // stage (kt&1) visible to all waves
        if (kt < 15) load_regs(kt + 1);   // issue next tile's global loads NOW
        const unsigned short* S = (const unsigned short*)lds + (kt & 1) * STAGE;
        bf16x8 ah[4], al[4];
        #pragma unroll
        for (int mt = 0; mt < 4; mt++) {
            const int rr = mw + mt * 16 + l15;
            const int off = rr * 32 + (quad ^ swz(rr)) * 8;
            ah[mt] = *(const bf16x8*)&S[off];
            if (APL == 2) al[mt] = *(const bf16x8*)&S[4096 + off];
        }
        #pragma unroll
        for (int nr = 0; nr < NREP; nr++) {
            bf16x8 bb[4];
            #pragma unroll
            for (int nt = 0; nt < 4; nt++) {
                const int rr = nw + nt * 16 + l15;
                bb[nt] = *(const bf16x8*)&S[(APL + nr) * 4096 + rr * 32
                                            + (quad ^ swz(rr)) * 8];
            }
            #pragma unroll
            for (int mt = 0; mt < 4; mt++)
                #pragma unroll
                for (int nt = 0; nt < 4; nt++) {
                    acc[nr][mt][nt] = MFMA16(ah[mt], bb[nt], acc[nr][mt][nt]);
                    if (APL == 2) acc[nr][mt][nt] = MFMA16(al[mt], bb[nt], acc[nr][mt][nt]);
                }
        }
        if (kt < 15) store_lds((kt + 1) & 1);  // vmcnt wait lands here, post-MFMA
    }
    __syncthreads();                      // LDS free for epilogue reuse
}

// ---- qkv pipe: fp32 A -> SINGLE bf16 RTN plane in-register at store time ----
// Error budget: single-plane RTN x contributes ~1.1e-3 std on q/k/v (fp32 MFMA
// accumulation over K=512); predicted end-to-end absmax ~3-4e-3 < 6.7e-3 thr.
// Halves MFMA work (32/kt) and LDS (3 planes -> 53.8 KB -> 3 blocks/CU; grid
// 768 = 3x256 fully co-resident, zero tail).
__device__ __forceinline__ void gemm_pipe_qkv(
        const float* __restrict__ x, const unsigned short* __restrict__ b_bf,
        char* lds, int m0, int f0, int t, f32x4 (&acc)[2][4][4]) {
    const int w = t >> 6, lane = t & 63, l15 = lane & 15, quad = lane >> 4;
    const int mw = (w & 1) * 64, nw = (w >> 1) * 64;
    const int STAGE = 3 * 4096;           // planes: 0=A 1=B(f0) 2=B(f0+128)
    const int r = t >> 1;
    const int g0 = (t & 1) * 2;

    float4 af[4];                         // 16 fp32 of A row r, cols k0+g0*8..+16
    uint4 bregs[2][2];
    auto load_regs = [&](int kt) {
        const int k0 = kt * 32;
        const float* gA = x + (size_t)(m0 + r) * DMODEL + k0 + g0 * 8;
        #pragma unroll
        for (int i = 0; i < 4; i++) af[i] = ((const float4*)gA)[i];
        #pragma unroll
        for (int p = 0; p < 2; p++) {
            const unsigned short* g =
                b_bf + (size_t)(f0 + p * 128 + r) * DMODEL + k0 + g0 * 8;
            bregs[p][0] = *(const uint4*)g;
            bregs[p][1] = *(const uint4*)(g + 8);
        }
    };
    auto store_lds = [&](int stage) {
        unsigned short* S = (unsigned short*)lds + stage * STAGE;
        const int s0 = ((g0 ^ swz(r))) * 8;
        const int s1 = (((g0 + 1) ^ swz(r))) * 8;
        // pack 8 floats -> one uint4 of RTN bf16
        auto cvt8 = [](const float4 a, const float4 b) {
            const float f[8] = {a.x, a.y, a.z, a.w, b.x, b.y, b.z, b.w};
            unsigned hw[4];
            #pragma unroll
            for (int j = 0; j < 4; j++)
                hw[j] = (unsigned)bf16_rtn(f[2 * j])
                      | ((unsigned)bf16_rtn(f[2 * j + 1]) << 16);
            return make_uint4(hw[0], hw[1], hw[2], hw[3]);
        };
        unsigned short* Sa = S + r * 32;
        *(uint4*)&Sa[s0] = cvt8(af[0], af[1]);
        *(uint4*)&Sa[s1] = cvt8(af[2], af[3]);
        #pragma unroll
        for (int p = 0; p < 2; p++) {
            unsigned short* Sp = S + (1 + p) * 4096 + r * 32;
            *(uint4*)&Sp[s0] = bregs[p][0];
            *(uint4*)&Sp[s1] = bregs[p][1];
        }
    };

    load_regs(0);
    store_lds(0);
    for (int kt = 0; kt < 16; kt++) {
        __syncthreads();
        if (kt < 15) load_regs(kt + 1);
        const unsigned short* S = (const unsigned short*)lds + (kt & 1) * STAGE;
        bf16x8 ah[4];
        #pragma unroll
        for (int mt = 0; mt < 4; mt++) {
            const int rr = mw + mt * 16 + l15;
            ah[mt] = *(const bf16x8*)&S[rr * 32 + (quad ^ swz(rr)) * 8];
        }
        #pragma unroll
        for (int nr = 0; nr < 2; nr++) {
            bf16x8 bb[4];
            #pragma unroll
            for (int nt = 0; nt < 4; nt++) {
                const int rr = nw + nt * 16 + l15;
                bb[nt] = *(const bf16x8*)&S[(1 + nr) * 4096 + rr * 32
                                            + (quad ^ swz(rr)) * 8];
            }
            #pragma unroll
            for (int mt = 0; mt < 4; mt++)
                #pragma unroll
                for (int nt = 0; nt < 4; nt++)
                    acc[nr][mt][nt] = MFMA16(ah[mt], bb[nt], acc[nr][mt][nt]);
        }
        if (kt < 15) store_lds((kt + 1) & 1);
    }
    __syncthreads();
}

// ---------------- Kernel 1: QKV GEMM + RoPE (128x256 tile, single-plane A) ----
__global__ __launch_bounds__(256, 3) void qkv_mfma_kernel(
        const float* __restrict__ x, const unsigned short* __restrict__ wq_bf,
        unsigned short* __restrict__ q_bf, unsigned short* __restrict__ k_bf,
        unsigned short* __restrict__ v_th) {
    __shared__ __align__(16) char lds[49152 + 4608];   // 2x24KB stages (+T alias) + tables
    unsigned short* T = (unsigned short*)lds;          // 128 x TP transpose buffer
    float* t_cy = (float*)(lds + 49152);               // [4][16]
    float* t_sy = t_cy + 64;
    float* t_cx = t_sy + 64;                           // [32][16]
    float* t_sx = t_cx + 512;

    const int m0 = blockIdx.x * 128;
    const int f0 = blockIdx.y * 256;
    const int t = threadIdx.x;
    const int w = t >> 6, lane = t & 63, l15 = lane & 15, quad = lane >> 4;
    const int mw = (w & 1) * 64, nw = (w >> 1) * 64;
    const int sel = f0 >> 9;                // 0=q,1=k,2=v (same for both subtiles)
    const int bt = m0 >> 10;
    const int n0 = m0 & 1023;

    if (sel != 2) {
        for (int idx = t; idx < 576; idx += 256) {
            if (idx < 64) {
                const int yi = idx >> 4, j = idx & 15;
                const float pos = -1.0f + (float)((n0 >> 5) + yi) * (2.0f / 31.0f);
                float sv, cv; sincosf(pos * freq_of(j), &sv, &cv);
                t_sy[idx] = sv; t_cy[idx] = cv;
            } else {
                const int k2 = idx - 64, xi = k2 >> 4, j = k2 & 15;
                const float pos = -1.0f + (float)xi * (2.0f / 31.0f);
                float sv, cv; sincosf(pos * freq_of(j), &sv, &cv);
                t_sx[k2] = sv; t_cx[k2] = cv;
            }
        }
    }
    __syncthreads();

    f32x4 acc[2][4][4];
    #pragma unroll
    for (int nr = 0; nr < 2; nr++)
        #pragma unroll
        for (int mt = 0; mt < 4; mt++)
            #pragma unroll
            for (int nt = 0; nt < 4; nt++) acc[nr][mt][nt] = (f32x4){0.f, 0.f, 0.f, 0.f};

    gemm_pipe_qkv(x, wq_bf, lds, m0, f0, t, acc);

    #pragma unroll
    for (int nr = 0; nr < 2; nr++) {
        const int fs = f0 + nr * 128;
        if (sel != 2) {
            const float post = (sel == 0) ? QSCALE : 1.0f;
            #pragma unroll
            for (int mt = 0; mt < 4; mt++)
                #pragma unroll
                for (int nt = 0; nt < 4; nt++)
                    #pragma unroll
                    for (int rr = 0; rr < 4; rr++) {
                        const int ml = mw + mt * 16 + quad * 4 + rr;
                        const int dd = (nw + nt * 16 + l15) & 63;
                        const int j0 = (dd & 31) >> 1;
                        float c, s;
                        if (dd < 32) { c = t_cy[(ml >> 5) * 16 + j0]; s = t_sy[(ml >> 5) * 16 + j0]; }
                        else         { c = t_cx[(ml & 31) * 16 + j0]; s = t_sx[(ml & 31) * 16 + j0]; }
                        const float v = acc[nr][mt][nt][rr];
                        const float pv = __shfl_xor(v, 1);
                        acc[nr][mt][nt][rr] =
                            ((l15 & 1) ? (v * c + pv * s) : (v * c - pv * s)) * post;
                    }
        }

        if (sel == 2) {
            #pragma unroll
            for (int mt = 0; mt < 4; mt++)
                #pragma unroll
                for (int nt = 0; nt < 4; nt++) {
                    const int fl = nw + nt * 16 + l15;
                    const int mlb = mw + mt * 16 + quad * 4;
                    ushort4 pk = make_ushort4(
                        bf16_rtn(acc[nr][mt][nt][0]), bf16_rtn(acc[nr][mt][nt][1]),
                        bf16_rtn(acc[nr][mt][nt][2]), bf16_rtn(acc[nr][mt][nt][3]));
                    *(ushort4*)&T[fl * TP + mlb] = pk;
                }
        } else {
            #pragma unroll
            for (int mt = 0; mt < 4; mt++)
                #pragma unroll
                for (int nt = 0; nt < 4; nt++)
                    #pragma unroll
                    for (int rr = 0; rr < 4; rr++) {
                        const int ml = mw + mt * 16 + quad * 4 + rr;
                        const int fl = nw + nt * 16 + l15;
                        T[ml * TP + fl] = bf16_rtn(acc[nr][mt][nt][rr]);
                    }
        }
        __syncthreads();
        if (sel == 2) {
            #pragma unroll
            for (int p = 0; p < 8; p++) {
                const int idx = p * 256 + t;
                const int fl = idx >> 4, g8 = (idx & 15) * 8;
                const int head = ((fs + fl) >> 6) & 7;
                *(uint4*)(v_th + ((size_t)(bt * NH + head) * HD + ((fs + fl) & 63)) * NSEQ
                          + n0 + g8) = *(const uint4*)&T[fl * TP + g8];
            }
        } else {
            unsigned short* dst = (sel == 0) ? q_bf : k_bf;
            #pragma unroll
            for (int p = 0; p < 8; p++) {
                const int idx = p * 256 + t;
                const int ml = idx >> 4, g8 = (idx & 15) * 8;
                const int head = ((fs + g8) >> 6) & 7;
                *(uint4*)(dst + ((size_t)(bt * NH + head) * NSEQ + n0 + ml) * HD
                          + ((fs + g8) & 63)) = *(const uint4*)&T[ml * TP + g8];
            }
        }
        __syncthreads();
    }
}

// ---------------- Kernel 2: flash attention, QBLK=256 (2 mf sub-tiles/wave) ----
__global__ __launch_bounds__(256, 2) void attn_kernel(
        const unsigned short* __restrict__ q_bf, const unsigned short* __restrict__ k_bf,
        const unsigned short* __restrict__ v_th,
        unsigned short* __restrict__ o_bf) {
    __shared__ unsigned short Ks[2][64 * KVP];  // K tile [n][d], double-buffered
    __shared__ unsigned short Vs[2][64 * KVP];  // V^T tile [d][n], double-buffered

    const int bh = blockIdx.x;     // fastest dim -> XCD = bh & 7 for all 4 qt blocks
    const int qt = blockIdx.y;     // 0..3
    const int t = threadIdx.x;
    const int w = t >> 6;
    const int lane = t & 63;
    const int l31 = lane & 31;
    const int hi = lane >> 5;

    const size_t bh_nd = (size_t)bh * NSEQ * HD;
    const size_t bh_dn = (size_t)bh * HD * NSEQ;

    // Q B-fragments for two 32-row sub-tiles: qrow = qt*256 + w*64 + mf*32 + l31
    bf16x8 qfB[2][4];
    #pragma unroll
    for (int mf = 0; mf < 2; mf++) {
        const size_t rbase =
            bh_nd + (size_t)(qt * 256 + w * 64 + mf * 32 + l31) * HD + hi * 8;
        #pragma unroll
        for (int ds = 0; ds < 4; ds++)
            qfB[mf][ds] = *(const bf16x8*)(q_bf + rbase + ds * 16);
    }

    uint4 kr[2], vr[2];
    auto load_kv = [&](int kt) {
        #pragma unroll
        for (int p = 0; p < 2; p++) {
            const int cc = t + p * 256;
            const int r = cc >> 3, off8 = (cc & 7) * 8;
            kr[p] = *(const uint4*)(k_bf + bh_nd + (size_t)(kt * 64 + r) * HD + off8);
            vr[p] = *(const uint4*)(v_th + bh_dn + (size_t)r * NSEQ + kt * 64 + off8);
        }
    };
    auto store_kv = [&](int st) {
        #pragma unroll
        for (int p = 0; p < 2; p++) {
            const int cc = t + p * 256;
            const int r = cc >> 3, off8 = (cc & 7) * 8;
            *(uint4*)&Ks[st][r * KVP + off8] = kr[p];
            *(uint4*)&Vs[st][r * KVP + off8] = vr[p];
        }
    };

    const bf16x8 ones = {(short)0x3F80, (short)0x3F80, (short)0x3F80, (short)0x3F80,
                         (short)0x3F80, (short)0x3F80, (short)0x3F80, (short)0x3F80};

    f32x16 o_acc[2][2], l_acc[2];
    #pragma unroll
    for (int i = 0; i < 16; i++) {
        o_acc[0][0][i] = 0.f; o_acc[0][1][i] = 0.f;
        o_acc[1][0][i] = 0.f; o_acc[1][1][i] = 0.f;
        l_acc[0][i] = 0.f; l_acc[1][i] = 0.f;
    }

    load_kv(0);
    store_kv(0);
    for (int kt = 0; kt < 16; kt++) {
        __syncthreads();                  // stage (kt&1) visible
        if (kt < 15) load_kv(kt + 1);     // prefetch next tile into VGPRs
        const unsigned short* K = Ks[kt & 1];
        const unsigned short* V = Vs[kt & 1];

        #pragma unroll
        for (int nt2 = 0; nt2 < 2; nt2++) {
            // ---- K fragments, shared by both mf chains ----
            bf16x8 kb[4];
            #pragma unroll
            for (int ds = 0; ds < 4; ds++)
                kb[ds] = *(const bf16x8*)&K[(nt2 * 32 + l31) * KVP + ds * 16 + hi * 8];

            // ---- S^T, softmax, pack: one P A-frag pair per mf ----
            u32x4 paw[2][2];
            #pragma unroll
            for (int mf = 0; mf < 2; mf++) {
                f32x16 s;
                #pragma unroll
                for (int i = 0; i < 16; i++) s[i] = 0.f;
                #pragma unroll
                for (int ds = 0; ds < 4; ds++) s = MFMA32(kb[ds], qfB[mf][ds], s);

                unsigned wv[8];
                #pragma unroll
                for (int i = 0; i < 8; i++) {
                    const float p0 = exp2f(s[2 * i]);
                    const float p1 = exp2f(s[2 * i + 1]);
                    asm("v_cvt_pk_bf16_f32 %0, %1, %2" : "=v"(wv[i]) : "v"(p0), "v"(p1));
                }
                // exchange halves: vdst.hi <-> vsrc.lo (first operand = lower-k word)
                asm volatile("v_permlane32_swap_b32 %0, %1" : "+v"(wv[0]), "+v"(wv[2]));
                asm volatile("v_permlane32_swap_b32 %0, %1" : "+v"(wv[1]), "+v"(wv[3]));
                asm volatile("v_permlane32_swap_b32 %0, %1" : "+v"(wv[4]), "+v"(wv[6]));
                asm volatile("v_permlane32_swap_b32 %0, %1" : "+v"(wv[5]), "+v"(wv[7]));
                paw[mf][0] = (u32x4){wv[0], wv[1], wv[2], wv[3]};
                paw[mf][1] = (u32x4){wv[4], wv[5], wv[6], wv[7]};
            }

            // ---- O += P·V, l += P·1; V fragments shared by both mf ----
            #pragma unroll
            for (int k2 = 0; k2 < 2; k2++) {
                bf16x8 vb[2];
                #pragma unroll
                for (int dt = 0; dt < 2; dt++)
                    vb[dt] = *(const bf16x8*)&V[(dt * 32 + l31) * KVP
                                 + (nt2 * 2 + k2) * 16 + hi * 8];
                #pragma unroll
                for (int mf = 0; mf < 2; mf++) {
                    const bf16x8 pa = __builtin_bit_cast(bf16x8, paw[mf][k2]);
                    l_acc[mf] = MFMA32(pa, ones, l_acc[mf]);
                    #pragma unroll
                    for (int dt = 0; dt < 2; dt++)
                        o_acc[mf][dt] = MFMA32(pa, vb[dt], o_acc[mf][dt]);
                }
            }
        }
        if (kt < 15) store_kv((kt + 1) & 1);  // vmcnt wait lands post-MFMA
    }

    // ---- epilogue: normalize by l; LDS bounce -> full-128B-line uint4 stores ----
    __syncthreads();                       // all waves done reading Ks/Vs
    unsigned short* Osh = &Ks[0][0];       // 256 rows x KVP pitch = 18432 els, exact fit
    #pragma unroll
    for (int mf = 0; mf < 2; mf++)
        #pragma unroll
        for (int r = 0; r < 16; r++) {
            const float inv = 1.0f / l_acc[mf][r];
            const int row = w * 64 + mf * 32 + (r & 3) + 8 * (r >> 2) + 4 * hi;
            #pragma unroll
            for (int dt = 0; dt < 2; dt++)
                Osh[row * KVP + dt * 32 + l31] = bf16_rtn(o_acc[mf][dt][r] * inv);
        }
    __syncthreads();
    const int btq = bh >> 3, head = bh & 7;
    #pragma unroll
    for (int p = 0; p < 8; p++) {
        const int idx = p * 256 + t;
        const int row = idx >> 3, g8 = (idx & 7) * 8;
        *(uint4*)(o_bf + ((size_t)(btq * NSEQ + qt * 256 + row)) * DMODEL
                  + head * HD + g8) = *(const uint4*)&Osh[row * KVP + g8];
    }
}

// ---------------- Kernel 3: output projection (128x256, NREP=2, pipelined) ----------------
__global__ __launch_bounds__(256, 2) void proj_mfma_kernel(
        const unsigned short* __restrict__ o_bf,
        const unsigned short* __restrict__ wo_bf,
        const float* __restrict__ b_out, float* __restrict__ out) {
    __shared__ __align__(16) char lds[49152];   // 2 x 24KB stages (3 planes)

    const int m0 = blockIdx.x * 128;
    const int f0 = blockIdx.y * 256;
    const int t = threadIdx.x;
    const int w = t >> 6, lane = t & 63, l15 = lane & 15, quad = lane >> 4;
    const int mw = (w & 1) * 64, nw = (w >> 1) * 64;

    f32x4 acc[2][4][4];
    #pragma unroll
    for (int nr = 0; nr < 2; nr++)
        #pragma unroll
        for (int mt = 0; mt < 4; mt++)
            #pragma unroll
            for (int nt = 0; nt < 4; nt++) acc[nr][mt][nt] = (f32x4){0.f, 0.f, 0.f, 0.f};

    gemm_reg_pipe<2, 2>(o_bf, o_bf, wo_bf, lds, m0, f0, t, acc);

    #pragma unroll
    for (int nr = 0; nr < 2; nr++) {
        const int fs = f0 + nr * 128;
        float bias_v[4];
        #pragma unroll
        for (int nt = 0; nt < 4; nt++) bias_v[nt] = b_out[fs + nw + nt * 16 + l15];
        #pragma unroll
        for (int mt = 0; mt < 4; mt++)
            #pragma unroll
            for (int nt = 0; nt < 4; nt++)
                #pragma unroll
                for (int rr = 0; rr < 4; rr++) {
                    const int m = m0 + mw + mt * 16 + quad * 4 + rr;
                    out[(size_t)m * DMODEL + fs + nw + nt * 16 + l15] =
                        acc[nr][mt][nt][rr] + bias_v[nt];
                }
    }
}

extern "C" void kernel_launch(void* const* d_in, const int* in_sizes, int n_in,
                              void* d_out, int out_size, void* d_ws, size_t ws_size,
                              hipStream_t stream) {
    const float* x  = (const float*)d_in[0];
    const float* wq = (const float*)d_in[1];
    const float* wo = (const float*)d_in[2];
    const float* bo = (const float*)d_in[3];
    float* out = (float*)d_out;

    const size_t per = (size_t)BH * NSEQ * HD;   // 8,388,608 elements
    unsigned short* o_bf = (unsigned short*)d_ws;
    unsigned short* q_bf = o_bf + per;
    unsigned short* k_bf = q_bf + per;
    unsigned short* v_th = k_bf + per;
    unsigned short* wq_bf = v_th + per;                   // 786,432 els
    unsigned short* wo_bf = wq_bf + (size_t)F3 * DMODEL;  // 262,144 els (~66 MiB total)

    cvt2_kernel<<<dim3((F3 * DMODEL + DMODEL * DMODEL) / 1024), 256, 0, stream>>>(
        wq, wq_bf, wo, wo_bf);
    qkv_mfma_kernel<<<dim3(NTOK / 128, F3 / 256), 256, 0, stream>>>(
        x, wq_bf, q_bf, k_bf, v_th);
    attn_kernel<<<dim3(BH, 4), 256, 0, stream>>>(
        q_bf, k_bf, v_th, o_bf);
    proj_mfma_kernel<<<dim3(NTOK / 128, DMODEL / 256), 256, 0, stream>>>(
        o_bf, wo_bf, bo, out);
}

// Round 9
// 209.447 us; speedup vs baseline: 1.3527x; 1.0422x over previous
//
#include <hip/hip_runtime.h>
#include <math.h>

#define NH 8
#define HD 64
#define NSEQ 1024
#define DMODEL 512
#define F3 1536
#define NTOK 16384
#define BH 128    // (B*T)*NH = 16*8
#define KVP 72    // attn K/V LDS pitch (bf16)
#define TP 136    // qkv epilogue transpose pitch (bf16)
#define QSCALE 0.1803368867f  // 0.125 * log2(e), folded into q; p = exp2(s')

typedef __attribute__((ext_vector_type(8))) short bf16x8;
typedef __attribute__((ext_vector_type(4))) float f32x4;
typedef __attribute__((ext_vector_type(16))) float f32x16;
typedef __attribute__((ext_vector_type(4))) unsigned int u32x4;
#define MFMA16(a, b, c) __builtin_amdgcn_mfma_f32_16x16x32_bf16(a, b, c, 0, 0, 0)
#define MFMA32(a, b, c) __builtin_amdgcn_mfma_f32_32x32x16_bf16(a, b, c, 0, 0, 0)

__device__ __forceinline__ float freq_of(int j) {
    return 3.14159265358979323846f * (1.0f + (float)j * (127.0f / 15.0f));
}
__device__ __forceinline__ unsigned short bf16_rtn(float x) {
    unsigned u = __builtin_bit_cast(unsigned, x);
    return (unsigned short)((u + 0x7FFF + ((u >> 16) & 1)) >> 16);  // round-nearest-even
}
// 2-bit LDS swizzle key for row r (permutes 16-B col-groups within a 64-B row)
__device__ __forceinline__ int swz(int r) { return (r & 3) ^ ((r >> 2) & 3); }

// ---------------- Kernel 0: fp32 -> bf16 RTN, both weight tensors ----------------
__global__ __launch_bounds__(256) void cvt2_kernel(
        const float* __restrict__ wq, unsigned short* __restrict__ wq_bf,
        const float* __restrict__ wo, unsigned short* __restrict__ wo_bf) {
    const int b = blockIdx.x;
    const float* src;
    unsigned short* dst;
    int i;
    if (b < F3 * DMODEL / 1024) { src = wq; dst = wq_bf; i = b * 256 + threadIdx.x; }
    else { src = wo; dst = wo_bf; i = (b - F3 * DMODEL / 1024) * 256 + threadIdx.x; }
    const float4 v = ((const float4*)src)[i];
    ((ushort4*)dst)[i] = make_ushort4(bf16_rtn(v.x), bf16_rtn(v.y),
                                      bf16_rtn(v.z), bf16_rtn(v.w));
}

// ---- register-staged pipelined GEMM core (generic bf16 A): 128x(128*NREP), BK=32 ----
template<int PLANES, int NREP>
__device__ __forceinline__ void gemm_reg_pipe(
        const unsigned short* __restrict__ a_hi, const unsigned short* __restrict__ a_lo,
        const unsigned short* __restrict__ b_bf,
        char* lds, int m0, int f0, int t, f32x4 (&acc)[NREP][4][4]) {
    const int w = t >> 6, lane = t & 63, l15 = lane & 15, quad = lane >> 4;
    const int mw = (w & 1) * 64, nw = (w >> 1) * 64;
    const int APL = PLANES - 1;           // A planes
    const int NPL = APL + NREP;           // total planes
    const int STAGE = NPL * 4096;         // elements per stage
    const int r = t >> 1;                 // 0..127: row this thread stages
    const int g0 = (t & 1) * 2;           // first of two 16-B col-groups

    uint4 regs[NPL][2];
    auto load_regs = [&](int kt) {
        const int k0 = kt * 32;
        #pragma unroll
        for (int p = 0; p < NPL; p++) {
            const unsigned short* src = (p < APL) ? (p == 0 ? a_hi : a_lo) : b_bf;
            const int row0 = (p < APL) ? m0 : (f0 + (p - APL) * 128);
            const unsigned short* g = src + (size_t)(row0 + r) * DMODEL + k0 + g0 * 8;
            regs[p][0] = *(const uint4*)g;
            regs[p][1] = *(const uint4*)(g + 8);
        }
    };
    auto store_lds = [&](int stage) {
        unsigned short* S = (unsigned short*)lds + stage * STAGE;
        const int s0 = ((g0 ^ swz(r))) * 8;
        const int s1 = (((g0 + 1) ^ swz(r))) * 8;
        #pragma unroll
        for (int p = 0; p < NPL; p++) {
            unsigned short* Sp = S + p * 4096 + r * 32;
            *(uint4*)&Sp[s0] = regs[p][0];
            *(uint4*)&Sp[s1] = regs[p][1];
        }
    };

    load_regs(0);
    store_lds(0);
    for (int kt = 0; kt < 16; kt++) {
        __syncthreads();                  // stage (kt&1) visible to all waves
        if (kt < 15) load_regs(kt + 1);   // issue next tile's global loads NOW
        const unsigned short* S = (const unsigned short*)lds + (kt & 1) * STAGE;
        bf16x8 ah[4], al[4];
        #pragma unroll
        for (int mt = 0; mt < 4; mt++) {
            const int rr = mw + mt * 16 + l15;
            const int off = rr * 32 + (quad ^ swz(rr)) * 8;
            ah[mt] = *(const bf16x8*)&S[off];
            if (APL == 2) al[mt] = *(const bf16x8*)&S[4096 + off];
        }
        #pragma unroll
        for (int nr = 0; nr < NREP; nr++) {
            bf16x8 bb[4];
            #pragma unroll
            for (int nt = 0; nt < 4; nt++) {
                const int rr = nw + nt * 16 + l15;
                bb[nt] = *(const bf16x8*)&S[(APL + nr) * 4096 + rr * 32
                                            + (quad ^ swz(rr)) * 8];
            }
            #pragma unroll
            for (int mt = 0; mt < 4; mt++)
                #pragma unroll
                for (int nt = 0; nt < 4; nt++) {
                    acc[nr][mt][nt] = MFMA16(ah[mt], bb[nt], acc[nr][mt][nt]);
                    if (APL == 2) acc[nr][mt][nt] = MFMA16(al[mt], bb[nt], acc[nr][mt][nt]);
                }
        }
        if (kt < 15) store_lds((kt + 1) & 1);  // vmcnt wait lands here, post-MFMA
    }
    __syncthreads();                      // LDS free for epilogue reuse
}

// ---- qkv pipe: fp32 A -> SINGLE bf16 RTN plane in-register at store time ----
__device__ __forceinline__ void gemm_pipe_qkv(
        const float* __restrict__ x, const unsigned short* __restrict__ b_bf,
        char* lds, int m0, int f0, int t, f32x4 (&acc)[2][4][4]) {
    const int w = t >> 6, lane = t & 63, l15 = lane & 15, quad = lane >> 4;
    const int mw = (w & 1) * 64, nw = (w >> 1) * 64;
    const int STAGE = 3 * 4096;           // planes: 0=A 1=B(f0) 2=B(f0+128)
    const int r = t >> 1;
    const int g0 = (t & 1) * 2;

    float4 af[4];                         // 16 fp32 of A row r, cols k0+g0*8..+16
    uint4 bregs[2][2];
    auto load_regs = [&](int kt) {
        const int k0 = kt * 32;
        const float* gA = x + (size_t)(m0 + r) * DMODEL + k0 + g0 * 8;
        #pragma unroll
        for (int i = 0; i < 4; i++) af[i] = ((const float4*)gA)[i];
        #pragma unroll
        for (int p = 0; p < 2; p++) {
            const unsigned short* g =
                b_bf + (size_t)(f0 + p * 128 + r) * DMODEL + k0 + g0 * 8;
            bregs[p][0] = *(const uint4*)g;
            bregs[p][1] = *(const uint4*)(g + 8);
        }
    };
    auto store_lds = [&](int stage) {
        unsigned short* S = (unsigned short*)lds + stage * STAGE;
        const int s0 = ((g0 ^ swz(r))) * 8;
        const int s1 = (((g0 + 1) ^ swz(r))) * 8;
        // pack 8 floats -> one uint4 of RTN bf16
        auto cvt8 = [](const float4 a, const float4 b) {
            const float f[8] = {a.x, a.y, a.z, a.w, b.x, b.y, b.z, b.w};
            unsigned hw[4];
            #pragma unroll
            for (int j = 0; j < 4; j++)
                hw[j] = (unsigned)bf16_rtn(f[2 * j])
                      | ((unsigned)bf16_rtn(f[2 * j + 1]) << 16);
            return make_uint4(hw[0], hw[1], hw[2], hw[3]);
        };
        unsigned short* Sa = S + r * 32;
        *(uint4*)&Sa[s0] = cvt8(af[0], af[1]);
        *(uint4*)&Sa[s1] = cvt8(af[2], af[3]);
        #pragma unroll
        for (int p = 0; p < 2; p++) {
            unsigned short* Sp = S + (1 + p) * 4096 + r * 32;
            *(uint4*)&Sp[s0] = bregs[p][0];
            *(uint4*)&Sp[s1] = bregs[p][1];
        }
    };

    load_regs(0);
    store_lds(0);
    for (int kt = 0; kt < 16; kt++) {
        __syncthreads();
        if (kt < 15) load_regs(kt + 1);
        const unsigned short* S = (const unsigned short*)lds + (kt & 1) * STAGE;
        bf16x8 ah[4];
        #pragma unroll
        for (int mt = 0; mt < 4; mt++) {
            const int rr = mw + mt * 16 + l15;
            ah[mt] = *(const bf16x8*)&S[rr * 32 + (quad ^ swz(rr)) * 8];
        }
        #pragma unroll
        for (int nr = 0; nr < 2; nr++) {
            bf16x8 bb[4];
            #pragma unroll
            for (int nt = 0; nt < 4; nt++) {
                const int rr = nw + nt * 16 + l15;
                bb[nt] = *(const bf16x8*)&S[(1 + nr) * 4096 + rr * 32
                                            + (quad ^ swz(rr)) * 8];
            }
            #pragma unroll
            for (int mt = 0; mt < 4; mt++)
                #pragma unroll
                for (int nt = 0; nt < 4; nt++)
                    acc[nr][mt][nt] = MFMA16(ah[mt], bb[nt], acc[nr][mt][nt]);
        }
        if (kt < 15) store_lds((kt + 1) & 1);
    }
    __syncthreads();
}

// ---------------- Kernel 1: QKV GEMM + RoPE (128x256 tile, single-plane A) ----
__global__ __launch_bounds__(256, 3) void qkv_mfma_kernel(
        const float* __restrict__ x, const unsigned short* __restrict__ wq_bf,
        unsigned short* __restrict__ q_bf, unsigned short* __restrict__ k_bf,
        unsigned short* __restrict__ v_th) {
    __shared__ __align__(16) char lds[49152 + 4608];   // 2x24KB stages (+T alias) + tables
    unsigned short* T = (unsigned short*)lds;          // 128 x TP transpose buffer
    float* t_cy = (float*)(lds + 49152);               // [4][16]
    float* t_sy = t_cy + 64;
    float* t_cx = t_sy + 64;                           // [32][16]
    float* t_sx = t_cx + 512;

    const int m0 = blockIdx.x * 128;
    const int f0 = blockIdx.y * 256;
    const int t = threadIdx.x;
    const int w = t >> 6, lane = t & 63, l15 = lane & 15, quad = lane >> 4;
    const int mw = (w & 1) * 64, nw = (w >> 1) * 64;
    const int sel = f0 >> 9;                // 0=q,1=k,2=v (same for both subtiles)
    const int bt = m0 >> 10;
    const int n0 = m0 & 1023;

    if (sel != 2) {
        for (int idx = t; idx < 576; idx += 256) {
            if (idx < 64) {
                const int yi = idx >> 4, j = idx & 15;
                const float pos = -1.0f + (float)((n0 >> 5) + yi) * (2.0f / 31.0f);
                float sv, cv; sincosf(pos * freq_of(j), &sv, &cv);
                t_sy[idx] = sv; t_cy[idx] = cv;
            } else {
                const int k2 = idx - 64, xi = k2 >> 4, j = k2 & 15;
                const float pos = -1.0f + (float)xi * (2.0f / 31.0f);
                float sv, cv; sincosf(pos * freq_of(j), &sv, &cv);
                t_sx[k2] = sv; t_cx[k2] = cv;
            }
        }
    }
    __syncthreads();

    f32x4 acc[2][4][4];
    #pragma unroll
    for (int nr = 0; nr < 2; nr++)
        #pragma unroll
        for (int mt = 0; mt < 4; mt++)
            #pragma unroll
            for (int nt = 0; nt < 4; nt++) acc[nr][mt][nt] = (f32x4){0.f, 0.f, 0.f, 0.f};

    gemm_pipe_qkv(x, wq_bf, lds, m0, f0, t, acc);

    #pragma unroll
    for (int nr = 0; nr < 2; nr++) {
        const int fs = f0 + nr * 128;
        if (sel != 2) {
            const float post = (sel == 0) ? QSCALE : 1.0f;
            #pragma unroll
            for (int mt = 0; mt < 4; mt++)
                #pragma unroll
                for (int nt = 0; nt < 4; nt++)
                    #pragma unroll
                    for (int rr = 0; rr < 4; rr++) {
                        const int ml = mw + mt * 16 + quad * 4 + rr;
                        const int dd = (nw + nt * 16 + l15) & 63;
                        const int j0 = (dd & 31) >> 1;
                        float c, s;
                        if (dd < 32) { c = t_cy[(ml >> 5) * 16 + j0]; s = t_sy[(ml >> 5) * 16 + j0]; }
                        else         { c = t_cx[(ml & 31) * 16 + j0]; s = t_sx[(ml & 31) * 16 + j0]; }
                        const float v = acc[nr][mt][nt][rr];
                        const float pv = __shfl_xor(v, 1);
                        acc[nr][mt][nt][rr] =
                            ((l15 & 1) ? (v * c + pv * s) : (v * c - pv * s)) * post;
                    }
        }

        if (sel == 2) {
            #pragma unroll
            for (int mt = 0; mt < 4; mt++)
                #pragma unroll
                for (int nt = 0; nt < 4; nt++) {
                    const int fl = nw + nt * 16 + l15;
                    const int mlb = mw + mt * 16 + quad * 4;
                    ushort4 pk = make_ushort4(
                        bf16_rtn(acc[nr][mt][nt][0]), bf16_rtn(acc[nr][mt][nt][1]),
                        bf16_rtn(acc[nr][mt][nt][2]), bf16_rtn(acc[nr][mt][nt][3]));
                    *(ushort4*)&T[fl * TP + mlb] = pk;
                }
        } else {
            #pragma unroll
            for (int mt = 0; mt < 4; mt++)
                #pragma unroll
                for (int nt = 0; nt < 4; nt++)
                    #pragma unroll
                    for (int rr = 0; rr < 4; rr++) {
                        const int ml = mw + mt * 16 + quad * 4 + rr;
                        const int fl = nw + nt * 16 + l15;
                        T[ml * TP + fl] = bf16_rtn(acc[nr][mt][nt][rr]);
                    }
        }
        __syncthreads();
        if (sel == 2) {
            #pragma unroll
            for (int p = 0; p < 8; p++) {
                const int idx = p * 256 + t;
                const int fl = idx >> 4, g8 = (idx & 15) * 8;
                const int head = ((fs + fl) >> 6) & 7;
                *(uint4*)(v_th + ((size_t)(bt * NH + head) * HD + ((fs + fl) & 63)) * NSEQ
                          + n0 + g8) = *(const uint4*)&T[fl * TP + g8];
            }
        } else {
            unsigned short* dst = (sel == 0) ? q_bf : k_bf;
            #pragma unroll
            for (int p = 0; p < 8; p++) {
                const int idx = p * 256 + t;
                const int ml = idx >> 4, g8 = (idx & 15) * 8;
                const int head = ((fs + g8) >> 6) & 7;
                *(uint4*)(dst + ((size_t)(bt * NH + head) * NSEQ + n0 + ml) * HD
                          + ((fs + g8) & 63)) = *(const uint4*)&T[ml * TP + g8];
            }
        }
        __syncthreads();
    }
}

// ---------------- Kernel 2: flash attention, 8 waves x 32 q-rows, QBLK=256 ----
// 512-thread blocks double waves/SIMD (2->4) to hide the VALU-heavy softmax
// under MFMA. Row-sum l via in-lane fp32 tree-adds + shfl_xor(32) (drops the
// ones-MFMA: -32 MFMA32/kt/block, -16 VGPR). S seeded from persistent zero16.
// VGPR must stay <=128 for 4 waves/SIMD.
__global__ __launch_bounds__(512, 2) void attn_kernel(
        const unsigned short* __restrict__ q_bf, const unsigned short* __restrict__ k_bf,
        const unsigned short* __restrict__ v_th,
        unsigned short* __restrict__ o_bf) {
    __shared__ unsigned short Ks[2][64 * KVP];  // K tile [n][d], double-buffered
    __shared__ unsigned short Vs[2][64 * KVP];  // V^T tile [d][n], double-buffered
    __shared__ float Lsh[256];                  // per-row 1/l broadcast

    const int bh = blockIdx.x;     // fastest dim -> XCD = bh & 7 for all 4 qt blocks
    const int qt = blockIdx.y;     // 0..3
    const int t = threadIdx.x;     // 0..511
    const int w = t >> 6;          // 0..7: wave owns 32 q-rows
    const int lane = t & 63;
    const int l31 = lane & 31;
    const int hi = lane >> 5;

    const size_t bh_nd = (size_t)bh * NSEQ * HD;
    const size_t bh_dn = (size_t)bh * HD * NSEQ;

    // Q B-fragments: qrow = qt*256 + w*32 + l31
    bf16x8 qfB[4];
    {
        const size_t rbase =
            bh_nd + (size_t)(qt * 256 + w * 32 + l31) * HD + hi * 8;
        #pragma unroll
        for (int ds = 0; ds < 4; ds++)
            qfB[ds] = *(const bf16x8*)(q_bf + rbase + ds * 16);
    }

    // staging: 512 threads x 1 uint4 each for K and V (64x64 tile each)
    const int sr = t >> 3, soff = (t & 7) * 8;
    uint4 kr, vr;
    auto load_kv = [&](int kt) {
        kr = *(const uint4*)(k_bf + bh_nd + (size_t)(kt * 64 + sr) * HD + soff);
        vr = *(const uint4*)(v_th + bh_dn + (size_t)sr * NSEQ + kt * 64 + soff);
    };
    auto store_kv = [&](int st) {
        *(uint4*)&Ks[st][sr * KVP + soff] = kr;
        *(uint4*)&Vs[st][sr * KVP + soff] = vr;
    };

    f32x16 o_acc[2], zero16;
    float l_sum = 0.f;
    #pragma unroll
    for (int i = 0; i < 16; i++) {
        o_acc[0][i] = 0.f; o_acc[1][i] = 0.f; zero16[i] = 0.f;
    }

    load_kv(0);
    store_kv(0);
    for (int kt = 0; kt < 16; kt++) {
        __syncthreads();                  // stage (kt&1) visible
        if (kt < 15) load_kv(kt + 1);     // prefetch next tile into VGPRs
        const unsigned short* K = Ks[kt & 1];
        const unsigned short* V = Vs[kt & 1];

        #pragma unroll
        for (int nt2 = 0; nt2 < 2; nt2++) {
            bf16x8 kb[4];
            #pragma unroll
            for (int ds = 0; ds < 4; ds++)
                kb[ds] = *(const bf16x8*)&K[(nt2 * 32 + l31) * KVP + ds * 16 + hi * 8];

            // ---- S^T = K · Q^T (zero16-seeded) ----
            __builtin_amdgcn_s_setprio(1);
            f32x16 s = MFMA32(kb[0], qfB[0], zero16);
            #pragma unroll
            for (int ds = 1; ds < 4; ds++) s = MFMA32(kb[ds], qfB[ds], s);
            __builtin_amdgcn_s_setprio(0);

            // ---- p = exp2(s); accumulate l in-lane; pack pairs to bf16 ----
            unsigned wv[8];
            float pp[8];
            #pragma unroll
            for (int i = 0; i < 8; i++) {
                const float p0 = exp2f(s[2 * i]);
                const float p1 = exp2f(s[2 * i + 1]);
                pp[i] = p0 + p1;
                asm("v_cvt_pk_bf16_f32 %0, %1, %2" : "=v"(wv[i]) : "v"(p0), "v"(p1));
            }
            l_sum += ((pp[0] + pp[1]) + (pp[2] + pp[3]))
                   + ((pp[4] + pp[5]) + (pp[6] + pp[7]));

            // ---- exchange halves: vdst.hi <-> vsrc.lo (first operand = lower-k word)
            asm volatile("v_permlane32_swap_b32 %0, %1" : "+v"(wv[0]), "+v"(wv[2]));
            asm volatile("v_permlane32_swap_b32 %0, %1" : "+v"(wv[1]), "+v"(wv[3]));
            asm volatile("v_permlane32_swap_b32 %0, %1" : "+v"(wv[4]), "+v"(wv[6]));
            asm volatile("v_permlane32_swap_b32 %0, %1" : "+v"(wv[5]), "+v"(wv[7]));

            // ---- O += P·V (P entirely in registers) ----
            __builtin_amdgcn_s_setprio(1);
            #pragma unroll
            for (int k2 = 0; k2 < 2; k2++) {
                const u32x4 paw = {wv[k2 * 4 + 0], wv[k2 * 4 + 1],
                                   wv[k2 * 4 + 2], wv[k2 * 4 + 3]};
                const bf16x8 pa = __builtin_bit_cast(bf16x8, paw);
                #pragma unroll
                for (int dt = 0; dt < 2; dt++) {
                    const bf16x8 vb = *(const bf16x8*)&V[(dt * 32 + l31) * KVP
                                         + (nt2 * 2 + k2) * 16 + hi * 8];
                    o_acc[dt] = MFMA32(pa, vb, o_acc[dt]);
                }
            }
            __builtin_amdgcn_s_setprio(0);
        }
        if (kt < 15) store_kv((kt + 1) & 1);  // vmcnt wait lands post-MFMA
    }

    // ---- combine row-sum halves; broadcast 1/l via LDS (intra-wave rows) ----
    l_sum += __shfl_xor(l_sum, 32);
    const float inv = 1.0f / l_sum;
    if (hi == 0) Lsh[w * 32 + l31] = inv;
    __syncthreads();                       // Lsh visible + Ks/Vs reads done

    // ---- epilogue: LDS bounce -> full-128B-line uint4 stores ----
    unsigned short* Osh = &Ks[0][0];       // 256 rows x KVP pitch = 18432 els (Ks+Vs)
    #pragma unroll
    for (int r = 0; r < 16; r++) {
        const int row32 = (r & 3) + 8 * (r >> 2) + 4 * hi;
        const float invr = Lsh[w * 32 + row32];
        const int row = w * 32 + row32;
        #pragma unroll
        for (int dt = 0; dt < 2; dt++)
            Osh[row * KVP + dt * 32 + l31] = bf16_rtn(o_acc[dt][r] * invr);
    }
    __syncthreads();
    const int btq = bh >> 3, head = bh & 7;
    #pragma unroll
    for (int p = 0; p < 4; p++) {
        const int idx = p * 512 + t;
        const int row = idx >> 3, g8 = (idx & 7) * 8;
        *(uint4*)(o_bf + ((size_t)(btq * NSEQ + qt * 256 + row)) * DMODEL
                  + head * HD + g8) = *(const uint4*)&Osh[row * KVP + g8];
    }
}

// ---------------- Kernel 3: output projection (128x256, NREP=2, pipelined) ----------------
__global__ __launch_bounds__(256, 2) void proj_mfma_kernel(
        const unsigned short* __restrict__ o_bf,
        const unsigned short* __restrict__ wo_bf,
        const float* __restrict__ b_out, float* __restrict__ out) {
    __shared__ __align__(16) char lds[49152];   // 2 x 24KB stages (3 planes)

    const int m0 = blockIdx.x * 128;
    const int f0 = blockIdx.y * 256;
    const int t = threadIdx.x;
    const int w = t >> 6, lane = t & 63, l15 = lane & 15, quad = lane >> 4;
    const int mw = (w & 1) * 64, nw = (w >> 1) * 64;

    f32x4 acc[2][4][4];
    #pragma unroll
    for (int nr = 0; nr < 2; nr++)
        #pragma unroll
        for (int mt = 0; mt < 4; mt++)
            #pragma unroll
            for (int nt = 0; nt < 4; nt++) acc[nr][mt][nt] = (f32x4){0.f, 0.f, 0.f, 0.f};

    gemm_reg_pipe<2, 2>(o_bf, o_bf, wo_bf, lds, m0, f0, t, acc);

    #pragma unroll
    for (int nr = 0; nr < 2; nr++) {
        const int fs = f0 + nr * 128;
        float bias_v[4];
        #pragma unroll
        for (int nt = 0; nt < 4; nt++) bias_v[nt] = b_out[fs + nw + nt * 16 + l15];
        #pragma unroll
        for (int mt = 0; mt < 4; mt++)
            #pragma unroll
            for (int nt = 0; nt < 4; nt++)
                #pragma unroll
                for (int rr = 0; rr < 4; rr++) {
                    const int m = m0 + mw + mt * 16 + quad * 4 + rr;
                    out[(size_t)m * DMODEL + fs + nw + nt * 16 + l15] =
                        acc[nr][mt][nt][rr] + bias_v[nt];
                }
    }
}

extern "C" void kernel_launch(void* const* d_in, const int* in_sizes, int n_in,
                              void* d_out, int out_size, void* d_ws, size_t ws_size,
                              hipStream_t stream) {
    const float* x  = (const float*)d_in[0];
    const float* wq = (const float*)d_in[1];
    const float* wo = (const float*)d_in[2];
    const float* bo = (const float*)d_in[3];
    float* out = (float*)d_out;

    const size_t per = (size_t)BH * NSEQ * HD;   // 8,388,608 elements
    unsigned short* o_bf = (unsigned short*)d_ws;
    unsigned short* q_bf = o_bf + per;
    unsigned short* k_bf = q_bf + per;
    unsigned short* v_th = k_bf + per;
    unsigned short* wq_bf = v_th + per;                   // 786,432 els
    unsigned short* wo_bf = wq_bf + (size_t)F3 * DMODEL;  // 262,144 els (~66 MiB total)

    cvt2_kernel<<<dim3((F3 * DMODEL + DMODEL * DMODEL) / 1024), 256, 0, stream>>>(
        wq, wq_bf, wo, wo_bf);
    qkv_mfma_kernel<<<dim3(NTOK / 128, F3 / 256), 256, 0, stream>>>(
        x, wq_bf, q_bf, k_bf, v_th);
    attn_kernel<<<dim3(BH, 4), 512, 0, stream>>>(
        q_bf, k_bf, v_th, o_bf);
    proj_mfma_kernel<<<dim3(NTOK / 128, DMODEL / 256), 256, 0, stream>>>(
        o_bf, wo_bf, bo, out);
}